// Round 9
// baseline (702.695 us; speedup 1.0000x reference)
//
#include <hip/hip_runtime.h>

#define G    160
#define G3   (G*G*G)          // 4,096,000
#define NV   300000
#define EPS  1e-4f
#define CAP  24576            // per-tap pair capacity (expected ~21.7k, proven R4-R9)
#define CPAD 32               // counters padded: counts[idx*CPAD] = one 128B line each
#define PCAP 655360           // total pair capacity (measured ~565k, +16%)
#define TOTIDX 896            // counts int index: global pair allocator
#define NS1  (27*192)         // scat tiles in fused conv1 kernel (CAP/128 per tap)

typedef unsigned short u16;
typedef __attribute__((ext_vector_type(8))) short bf16x8;
typedef __attribute__((ext_vector_type(4))) float f32x4;

// ---- workspace layout (bytes) ----
// R11: R10's global cnt-class perm CRASHED (per-class allocators all started at 0
// -> perm collisions -> uninitialized perm -> OOB partial reads). Fix: BLOCK-LOCAL
// cnt sort — each k_pairs block permutes only its own 256-row window (LDS class
// count + serial 27-class scan + rank), bijective by construction. Waves in the
// gathers then see (near-)uniform partial-loop trip counts. k_prep fuses
// grid|bn1|weights; k_c1 fuses scat1|self1 (128-row tiles, R7-proven).
#define OFF_PART 0ull                          // PCAP*256 = 167,772,160
#define OFF_GRID 0ull                          // 16,384,000 (dies before partial writes)
#define OFF_PIN  167772160ull                  // 27*CAP*4 = 2,654,208
#define OFF_PDST (OFF_PIN  + 2654208ull)       // 27*CAP*4 = 2,654,208
#define OFF_RI   (OFF_PDST + 2654208ull)       // NV*4     = 1,200,000
#define OFF_PERM (OFF_RI   + 1200000ull)       // NV*4     = 1,200,000
#define OFF_CNT  (OFF_PERM + 1200000ull)       // 8192 (tap + total allocators)
#define OFF_H0   (OFF_CNT  + 8192ull)          // NV*64*2  = 38,400,000
#define OFF_H1   (OFF_H0   + 38400000ull)      // NV*128*2 = 76,800,000
#define OFF_W1T  (OFF_H1   + 76800000ull)      // 27*128*64*2  (B^T layout [k][cout][cin])
#define OFF_W2T  (OFF_W1T  + 442368ull)        // 27*128*128*2
#define OFF_LINW (OFF_W2T  + 884736ull)        // 128*64*2
#define OFF_BNP  (OFF_LINW + 16384ull)         // 2*128*4 (BN2 scale|shift)
#define WS_NEED  (OFF_BNP  + 1024ull)          // ~292 MB (< R5's proven 322.7)

__device__ __forceinline__ u16 f2bf(float f) {   // fp32 -> bf16 RNE
  unsigned u = __float_as_uint(f);
  return (u16)((u + 0x7fffu + ((u >> 16) & 1u)) >> 16);
}
__device__ __forceinline__ float bf2f(u16 h) {
  return __uint_as_float(((unsigned)h) << 16);
}

// ---------- phase 1: pair lists + CSR segments + block-local cnt-sorted perm ----------
__global__ __launch_bounds__(256) void k_pairs(const int* __restrict__ pos,
                        const int* __restrict__ grid,
                        int* __restrict__ pin, int* __restrict__ pdst,
                        int* __restrict__ rowinfo, int* __restrict__ perm,
                        int* __restrict__ counts) {
  __shared__ int lcnt[27];
  __shared__ int wboff[27][4];
  __shared__ int gbase[27];
  __shared__ int lclass[27];
  __shared__ int coff[27];
  __shared__ int scan[256];
  __shared__ int sgb;
  int t = threadIdx.x, lane = t & 63, wv = t >> 6;
  if (t < 27) { lcnt[t] = 0; lclass[t] = 0; }
  int i = blockIdx.x * 256 + t;
  bool act = (i < NV);
  int p0 = 0, p1 = 1 << 20, p2 = 0;              // inactive threads -> always OOB
  if (act) { p0 = pos[3*i]; p1 = pos[3*i+1]; p2 = pos[3*i+2]; }
  __syncthreads();                               // lcnt/lclass zeroed

  int j[26];
  #pragma unroll
  for (int kk = 0; kk < 26; kk++) {              // all 26 loads independent & in flight
    int k = kk < 13 ? kk : kk + 1;
    int q0 = p0 + k/9 - 1, q1 = p1 + (k/3)%3 - 1, q2 = p2 + k%3 - 1;
    bool inb = (q0 >= 0 && q0 < G && q1 >= 0 && q1 < G && q2 >= 0 && q2 < G);
    int addr = inb ? (q0*G + q1)*G + q2 : 0;     // clamped: unconditional load
    int jj = grid[addr];
    j[kk] = inb ? jj : -1;
  }

  unsigned vmask = 0;                            // per-row valid-tap mask (kk order)
  #pragma unroll
  for (int kk = 0; kk < 26; kk++) if (j[kk] >= 0) vmask |= 1u << kk;
  int ci = __popc(vmask);

  int myrank = 0;
  if (act) myrank = atomicAdd(&lclass[ci], 1);   // LDS rank within block's cnt-class

  unsigned long long m[26];                      // wave-uniform -> SGPRs
  #pragma unroll
  for (int kk = 0; kk < 26; kk++) m[kk] = __ballot(j[kk] >= 0);

  #pragma unroll
  for (int kk = 0; kk < 26; kk++) {              // per-block aggregation in LDS
    int k = kk < 13 ? kk : kk + 1;
    if (lane == 0) wboff[k][wv] = atomicAdd(&lcnt[k], (int)__popcll(m[kk]));
  }
  scan[t] = ci;
  __syncthreads();                               // (also finalizes lclass counts)
  #pragma unroll
  for (int d = 1; d < 256; d <<= 1) {            // Hillis-Steele inclusive scan
    int val = (t >= d) ? scan[t - d] : 0;
    __syncthreads();
    scan[t] += val;
    __syncthreads();
  }
  if (t < 27 && t != 13)                         // concurrent atomics, separate L2 lines
    gbase[t] = atomicAdd(&counts[t * CPAD], lcnt[t]);
  if (t == 255) sgb = atomicAdd(&counts[TOTIDX], scan[255]);
  if (t == 0) {                                  // block-local class offsets (bijective)
    int s = 0;
    #pragma unroll
    for (int c = 0; c < 27; c++) { coff[c] = s; s += lclass[c]; }
  }
  __syncthreads();

  int rbase = sgb + scan[t] - ci;                // this row's CSR segment base
  int cw = (rbase + ci > PCAP) ? 0 : ci;         // overflow guard (never expected)
  if (act) {
    rowinfo[i] = (rbase << 5) | cw;
    perm[blockIdx.x * 256 + coff[ci] + myrank] = i;  // cnt-sorted within window
  }

  #pragma unroll
  for (int kk = 0; kk < 26; kk++) {
    if (j[kk] >= 0) {
      int k = kk < 13 ? kk : kk + 1;
      int slot = gbase[k] + wboff[k][wv] + (int)__popcll(m[kk] & ((1ull << lane) - 1ull));
      int dst = rbase + __popc(vmask & ((1u << kk) - 1u));
      if (slot < CAP) {
        pin[k*CAP + slot]  = j[kk];
        pdst[k*CAP + slot] = (dst < PCAP) ? dst : -1;
      }
    }
  }
}

// ---------- fused prep: BN1+ReLU->h0 | hash grid | weight cast + BN2 precompute ----------
#define NB_BN   18750                            // NV*16/256
#define NB_GRID 1172                             // (NV+255)/256
__global__ __launch_bounds__(256) void k_prep(const float* __restrict__ feat,
                          const int* __restrict__ pos, int* __restrict__ grid,
                          const float* __restrict__ g1, const float* __restrict__ b1,
                          const float* __restrict__ m1, const float* __restrict__ v1,
                          u16* __restrict__ h0,
                          const float* __restrict__ W1, const float* __restrict__ W2,
                          const float* __restrict__ linw,
                          const float* __restrict__ g2, const float* __restrict__ b2,
                          const float* __restrict__ m2, const float* __restrict__ v2,
                          u16* __restrict__ w1t, u16* __restrict__ w2t,
                          u16* __restrict__ lwt, float* __restrict__ bnp) {
  __shared__ float shf[8192];
  int b = blockIdx.x, t = threadIdx.x;
  if (b < NB_BN) {                                 // ---- BN1+ReLU -> bf16 h0 ----
    float* ss = shf; float* tt = shf + 64;
    if (t < 64) { float s = g1[t] * rsqrtf(v1[t] + EPS); ss[t] = s; tt[t] = b1[t] - m1[t]*s; }
    __syncthreads();
    long gt = (long)b * 256 + t;                   // one thread per 4 elems
    int c = (int)(gt & 15) * 4;
    float4 x = ((const float4*)feat)[gt];
    ushort4 q;
    q.x = f2bf(fmaxf(x.x*ss[c  ] + tt[c  ], 0.f));
    q.y = f2bf(fmaxf(x.y*ss[c+1] + tt[c+1], 0.f));
    q.z = f2bf(fmaxf(x.z*ss[c+2] + tt[c+2], 0.f));
    q.w = f2bf(fmaxf(x.w*ss[c+3] + tt[c+3], 0.f));
    ((ushort4*)h0)[gt] = q;
  } else if (b < NB_BN + NB_GRID) {                // ---- hash grid ----
    int i = (b - NB_BN) * 256 + t;
    if (i < NV)
      grid[(pos[3*i] * G + pos[3*i+1]) * G + pos[3*i+2]] = i;
  } else {                                         // ---- weights (56 blocks) ----
    int bb = b - NB_BN - NB_GRID;
    float* tmp = shf;
    if (bb < 27) {                                 // W1[k]: [64][128] -> [128][64]
      const float* src = W1 + bb * 8192;
      u16* dst = w1t + bb * 8192;
      for (int u = t; u < 8192; u += 256) tmp[u] = src[u];
      __syncthreads();
      for (int u = t; u < 8192; u += 256) { int c = u >> 6, a = u & 63; dst[c*64 + a] = f2bf(tmp[a*128 + c]); }
    } else if (bb < 54) {                          // W2[k]: [128][128]^T, two halves
      int k = bb - 27;
      const float* src = W2 + k * 16384;
      u16* dst = w2t + k * 16384;
      for (int h = 0; h < 2; h++) {
        for (int u = t; u < 8192; u += 256) tmp[u] = src[h*8192 + u];
        __syncthreads();
        for (int u = t; u < 8192; u += 256) { int c = u >> 6, a = u & 63; dst[c*128 + h*64 + a] = f2bf(tmp[a*128 + c]); }
        __syncthreads();
      }
    } else if (bb == 54) {                         // lin_w [128][64] already B^T
      for (int u = t; u < 8192; u += 256) lwt[u] = f2bf(linw[u]);
    } else {                                       // BN2 scale|shift
      if (t < 128) { float s = g2[t] * rsqrtf(v2[t] + EPS); bnp[t] = s; bnp[128 + t] = b2[t] - m2[t]*s; }
    }
  }
}

// ---------- GEMM building blocks (128x128 tile, 4 waves, 64x64 quadrants — R7-proven) ----------
template<int K, int RS>   // K: reduce dim; RS: global row stride (bf16 elems)
__device__ __forceinline__ void stage_rows(const u16* __restrict__ src, const int* sidx, u16* lds) {
  const int LPR = K / 8, RPI = 256 / LPR;          // 16B loaders per row, rows per iter
  int t = threadIdx.x, o = t % LPR, r0 = t / LPR;
  #pragma unroll
  for (int r = r0; r < 128; r += RPI) {
    int j = sidx[r];
    int4 val = make_int4(0, 0, 0, 0);
    if (j >= 0) val = *(const int4*)(src + (long)j * RS + o * 8);
    *(int4*)(lds + r * (K + 8) + o * 8) = val;     // +8 elem pad: low-order LDS banking
  }
}

__device__ __forceinline__ void stage_feat(const float* __restrict__ feat, int row0, u16* lds) {
  int t = threadIdx.x, o = t & 15, r0 = t >> 4;    // fp32->bf16 on the fly, K=64
  #pragma unroll
  for (int r = r0; r < 128; r += 16) {
    int row = row0 + r;
    float4 x = make_float4(0.f, 0.f, 0.f, 0.f);
    if (row < NV) x = *(const float4*)(feat + (long)row * 64 + o * 4);
    ushort4 q; q.x = f2bf(x.x); q.y = f2bf(x.y); q.z = f2bf(x.z); q.w = f2bf(x.w);
    *(ushort4*)(lds + r * 72 + o * 4) = q;
  }
}

template<int K>           // A from padded LDS; B-frags straight from L2-hot transposed weights
__device__ __forceinline__ void mma_tile(const u16* As, const u16* __restrict__ wt, f32x4 acc[4][4]) {
  int lane = threadIdx.x & 63, wave = threadIdx.x >> 6;
  int wr = (wave >> 1) * 64, wc = (wave & 1) * 64;
  int lr = lane & 15, lk = (lane >> 4) * 8;
  #pragma unroll
  for (int kk = 0; kk < K; kk += 32) {
    bf16x8 a[4], b[4];
    #pragma unroll
    for (int f = 0; f < 4; f++) a[f] = *(const bf16x8*)(As + (wr + f*16 + lr) * (K + 8) + kk + lk);
    #pragma unroll
    for (int f = 0; f < 4; f++) b[f] = *(const bf16x8*)(wt + (wc + f*16 + lr) * K + kk + lk);
    #pragma unroll
    for (int fr = 0; fr < 4; fr++)
      #pragma unroll
      for (int fc = 0; fc < 4; fc++)
        acc[fr][fc] = __builtin_amdgcn_mfma_f32_16x16x32_bf16(a[fr], b[fc], acc[fr][fc], 0, 0, 0);
  }
}

// Spill f32 acc -> bf16 LDS tile [128][136] (reuses the staging buffer).
__device__ __forceinline__ void spill_acc(const f32x4 acc[4][4], u16* As) {
  int t = threadIdx.x, lane = t & 63, wave = t >> 6;
  int wr = (wave >> 1) * 64, wc = (wave & 1) * 64, cr = (lane >> 4) * 4, cc = lane & 15;
  #pragma unroll
  for (int fr = 0; fr < 4; fr++)
    #pragma unroll
    for (int r = 0; r < 4; r++)
      #pragma unroll
      for (int fc = 0; fc < 4; fc++)
        As[(wr + fr*16 + cr + r) * 136 + wc + fc*16 + cc] = f2bf(acc[fr][fc][r]);
}

// ---------- fused conv1: scat taps (blocks < NS1) -> partial | self tap -> h1 ----------
__global__ __launch_bounds__(256, 4) void k_c1(const u16* __restrict__ h0,
                                               const u16* __restrict__ w1t,
                                               const int* __restrict__ pin,
                                               const int* __restrict__ pdst,
                                               const int* __restrict__ counts,
                                               u16* __restrict__ partial,
                                               u16* __restrict__ h1) {
  __shared__ __align__(16) u16 As[128 * 136];      // stage: [128][72]; epilogue: [128][136]
  __shared__ int sin[128], sdst[128];
  int bx = blockIdx.x, t = threadIdx.x;
  if (bx < NS1) {                                  // ---- scat path ----
    int k = bx / 192, base = (bx % 192) * 128;
    int cnt = counts[k * CPAD]; if (cnt > CAP) cnt = CAP;
    if (base >= cnt) return;                       // k==13 (cnt 0) and tail tiles exit
    if (t < 128) sin[t] = (base + t < cnt) ? pin[k*CAP + base + t] : -1;
    else         sdst[t - 128] = (base + t - 128 < cnt) ? pdst[k*CAP + base + t - 128] : -1;
    __syncthreads();
    stage_rows<64, 64>(h0, sin, As);
    __syncthreads();
    f32x4 acc[4][4] = {};
    mma_tile<64>(As, w1t + k * 8192, acc);
    __syncthreads();
    spill_acc(acc, As);
    __syncthreads();
    #pragma unroll
    for (int u = t; u < 2048; u += 256) {          // 256B-row stores to CSR destinations
      int r = u >> 4, o = u & 15;
      int d = sdst[r];
      if (d >= 0)
        *(int4*)(partial + (long)d * 128 + o * 8) = *(const int4*)(As + r * 136 + o * 8);
    }
  } else {                                         // ---- self path: dense tap 13 ----
    int row0 = (bx - NS1) * 128;
    if (t < 128) sin[t] = (row0 + t < NV) ? row0 + t : -1;
    __syncthreads();
    stage_rows<64, 64>(h0, sin, As);
    __syncthreads();
    f32x4 acc[4][4] = {};
    mma_tile<64>(As, w1t + 13 * 8192, acc);
    __syncthreads();
    spill_acc(acc, As);
    __syncthreads();
    #pragma unroll
    for (int u = t; u < 2048; u += 256) {
      int r = u >> 4, o = u & 15;
      if (row0 + r < NV)
        *(int4*)(h1 + (long)(row0 + r) * 128 + o * 8) = *(const int4*)(As + r * 136 + o * 8);
    }
  }
}

// ---------- conv2 scat: gather-GEMM K=128 -> bf16 partial rows ----------
__global__ __launch_bounds__(256, 4) void k_scat2(const u16* __restrict__ h1,
                                                  const u16* __restrict__ w2t,
                                                  const int* __restrict__ pin,
                                                  const int* __restrict__ pdst,
                                                  const int* __restrict__ counts,
                                                  u16* __restrict__ partial) {
  int k = blockIdx.y;
  int cnt = counts[k * CPAD]; if (cnt > CAP) cnt = CAP;
  int base = blockIdx.x * 128;
  if (base >= cnt) return;
  __shared__ __align__(16) u16 As[128 * 136];
  __shared__ int sin[128], sdst[128];
  int t = threadIdx.x;
  if (t < 128) sin[t] = (base + t < cnt) ? pin[k*CAP + base + t] : -1;
  else         sdst[t - 128] = (base + t - 128 < cnt) ? pdst[k*CAP + base + t - 128] : -1;
  __syncthreads();
  stage_rows<128, 128>(h1, sin, As);
  __syncthreads();
  f32x4 acc[4][4] = {};
  mma_tile<128>(As, w2t + k * 16384, acc);
  __syncthreads();
  spill_acc(acc, As);
  __syncthreads();
  #pragma unroll
  for (int u = t; u < 2048; u += 256) {
    int r = u >> 4, o = u & 15;
    int d = sdst[r];
    if (d >= 0)
      *(int4*)(partial + (long)d * 128 + o * 8) = *(const int4*)(As + r * 136 + o * 8);
  }
}

// NiN skip + self tap for conv2; writes bf16 IN PLACE over h1 (own tile staged first).
__global__ __launch_bounds__(256, 4) void k_self2(const float* __restrict__ feat,
                                                  const u16* __restrict__ lwt,
                                                  u16* __restrict__ h1,
                                                  const u16* __restrict__ w2t) {
  __shared__ __align__(16) u16 As[128 * 136];
  __shared__ int sidx[128];
  int t = threadIdx.x, row0 = blockIdx.x * 128;
  if (t < 128) sidx[t] = (row0 + t < NV) ? row0 + t : -1;
  __syncthreads();
  f32x4 acc[4][4] = {};
  stage_feat(feat, row0, As);                      // K=64 NiN pass (stride 72 region)
  __syncthreads();
  mma_tile<64>(As, lwt, acc);
  __syncthreads();
  stage_rows<128, 128>(h1, sidx, As);              // K=128 self pass (stride 136)
  __syncthreads();
  mma_tile<128>(As, w2t + 13 * 16384, acc);
  __syncthreads();
  spill_acc(acc, As);
  __syncthreads();
  #pragma unroll
  for (int u = t; u < 2048; u += 256) {
    int r = u >> 4, o = u & 15;
    if (row0 + r < NV)
      *(int4*)(h1 + (long)(row0 + r) * 128 + o * 8) = *(const int4*)(As + r * 136 + o * 8);
  }
}

// ---------- pure gather kernels: cnt-uniform waves via block-local perm ----------
// c[32] = self(bf16) + sum of cnt CONTIGUOUS partial rows starting at base.
__device__ __forceinline__ void gather_csr(int row, int q, int base, int cnt,
                                           const u16* __restrict__ sp,
                                           const u16* __restrict__ partial,
                                           float c[32]) {
  bf16x8 s0[4];
  const u16* srow = sp + (long)row * 128 + q * 32;
  #pragma unroll
  for (int u = 0; u < 4; u++) s0[u] = *(const bf16x8*)(srow + u * 8);
  #pragma unroll
  for (int u = 0; u < 4; u++)
    #pragma unroll
    for (int e = 0; e < 8; e++) c[u*8 + e] = bf2f((u16)s0[u][e]);
  const u16* pr = partial + (long)base * 128 + q * 32;
  int p = 0;
  for (; p + 2 <= cnt; p += 2) {                   // 2-wide: 8 independent 16B loads in flight
    bf16x8 a[4], b[4];
    #pragma unroll
    for (int u = 0; u < 4; u++) a[u] = *(const bf16x8*)(pr + u * 8);
    #pragma unroll
    for (int u = 0; u < 4; u++) b[u] = *(const bf16x8*)(pr + 128 + u * 8);
    #pragma unroll
    for (int u = 0; u < 4; u++)
      #pragma unroll
      for (int e = 0; e < 8; e++) c[u*8 + e] += bf2f((u16)a[u][e]) + bf2f((u16)b[u][e]);
    pr += 256;
  }
  if (p < cnt) {
    bf16x8 a[4];
    #pragma unroll
    for (int u = 0; u < 4; u++) a[u] = *(const bf16x8*)(pr + u * 8);
    #pragma unroll
    for (int u = 0; u < 4; u++)
      #pragma unroll
      for (int e = 0; e < 8; e++) c[u*8 + e] += bf2f((u16)a[u][e]);
  }
}

// conv1: h1 = bf16(ReLU(BN2(self + partials)))  -- in place over h1 (self pre-BN)
__global__ __launch_bounds__(256) void k_gather1(const int* __restrict__ perm,
                                                 const int* __restrict__ rowinfo,
                                                 const u16* __restrict__ partial,
                                                 const float* __restrict__ bnp,
                                                 u16* __restrict__ h1) {
  long tid = (long)blockIdx.x * 256 + threadIdx.x;
  int idx = (int)(tid >> 2), q = (int)(tid & 3);
  if (idx >= NV) return;
  int row = perm[idx];                             // cnt-sorted window: uniform loop/wave
  int ri = rowinfo[row];
  int base = (int)((unsigned)ri >> 5), cnt = ri & 31;
  float c[32];
  gather_csr(row, q, base, cnt, h1, partial, c);
  int col0 = q * 32;
  unsigned w[16];
  #pragma unroll
  for (int e = 0; e < 16; e++) {
    float o0 = fmaxf(c[2*e  ] * bnp[col0 + 2*e  ] + bnp[128 + col0 + 2*e  ], 0.f);
    float o1 = fmaxf(c[2*e+1] * bnp[col0 + 2*e+1] + bnp[128 + col0 + 2*e+1], 0.f);
    w[e] = (unsigned)f2bf(o0) | ((unsigned)f2bf(o1) << 16);
  }
  int4* dst = (int4*)(h1 + (long)row * 128 + col0);
  #pragma unroll
  for (int u = 0; u < 4; u++) dst[u] = make_int4(w[4*u], w[4*u+1], w[4*u+2], w[4*u+3]);
}

// conv2: out = f32(self(+NiN) + partials); self rides in h1 (from k_self2)
__global__ __launch_bounds__(256) void k_gather2(const int* __restrict__ perm,
                                                 const int* __restrict__ rowinfo,
                                                 const u16* __restrict__ partial,
                                                 const u16* __restrict__ h1,
                                                 float* __restrict__ out) {
  long tid = (long)blockIdx.x * 256 + threadIdx.x;
  int idx = (int)(tid >> 2), q = (int)(tid & 3);
  if (idx >= NV) return;
  int row = perm[idx];                             // cnt-sorted window: uniform loop/wave
  int ri = rowinfo[row];
  int base = (int)((unsigned)ri >> 5), cnt = ri & 31;
  float c[32];
  gather_csr(row, q, base, cnt, h1, partial, c);
  float* dst = out + (long)row * 128 + q * 32;
  #pragma unroll
  for (int u = 0; u < 8; u++) {
    f32x4 v;
    #pragma unroll
    for (int e = 0; e < 4; e++) v[e] = c[u*4 + e];
    *(f32x4*)(dst + u * 4) = v;
  }
}

extern "C" void kernel_launch(void* const* d_in, const int* in_sizes, int n_in,
                              void* d_out, int out_size, void* d_ws, size_t ws_size,
                              hipStream_t stream) {
  const float* feat = (const float*)d_in[0];
  const int*   pos  = (const int*)d_in[1];
  const float* linw = (const float*)d_in[2];
  const float* g1 = (const float*)d_in[3], *b1 = (const float*)d_in[4];
  const float* m1 = (const float*)d_in[5], *v1 = (const float*)d_in[6];
  const float* W1 = (const float*)d_in[7];
  const float* g2 = (const float*)d_in[8], *b2 = (const float*)d_in[9];
  const float* m2 = (const float*)d_in[10], *v2 = (const float*)d_in[11];
  const float* W2 = (const float*)d_in[12];

  if (ws_size < WS_NEED) return;  // insufficient scratch; fail visibly rather than corrupt

  char* ws = (char*)d_ws;
  u16*   partial = (u16*)(ws + OFF_PART);
  int*   grid    = (int*)(ws + OFF_GRID);          // overlays partial head, dead before it
  int*   pin     = (int*)(ws + OFF_PIN);
  int*   pdst    = (int*)(ws + OFF_PDST);
  int*   rowinfo = (int*)(ws + OFF_RI);
  int*   perm    = (int*)(ws + OFF_PERM);
  int*   counts  = (int*)(ws + OFF_CNT);
  u16*   h0      = (u16*)(ws + OFF_H0);
  u16*   h1      = (u16*)(ws + OFF_H1);
  u16*   w1t     = (u16*)(ws + OFF_W1T);
  u16*   w2t     = (u16*)(ws + OFF_W2T);
  u16*   lwt     = (u16*)(ws + OFF_LINW);
  float* bnp     = (float*)(ws + OFF_BNP);
  float* out     = (float*)d_out;

  hipMemsetAsync(grid,  0xFF, (size_t)G3 * 4, stream);       // grid = -1
  hipMemsetAsync(counts, 0, 8192, stream);                   // tap + total allocators

  k_prep <<<NB_BN + NB_GRID + 56, 256, 0, stream>>>(feat, pos, grid, g1, b1, m1, v1, h0,
                                                    W1, W2, linw, g2, b2, m2, v2,
                                                    w1t, w2t, lwt, bnp);
  k_pairs<<<(NV + 255) / 256, 256, 0, stream>>>(pos, grid, pin, pdst, rowinfo, perm, counts);

  int nself = (NV + 127) / 128;                    // 2344 self tiles
  dim3 gg(((long)NV * 4 + 255) / 256);
  k_c1     <<<NS1 + nself, 256, 0, stream>>>(h0, w1t, pin, pdst, counts, partial, h1);
  k_gather1<<<gg, 256, 0, stream>>>(perm, rowinfo, partial, bnp, h1);
  k_scat2  <<<dim3(192, 27), 256, 0, stream>>>(h1, w2t, pin, pdst, counts, partial);
  k_self2  <<<nself, 256, 0, stream>>>(feat, lwt, h1, w2t);
  k_gather2<<<gg, 256, 0, stream>>>(perm, rowinfo, partial, h1, out);
}

// Round 12
// 670.860 us; speedup vs baseline: 1.0475x; 1.0475x over previous
//
#include <hip/hip_runtime.h>

#define G    160
#define G3   (G*G*G)          // 4,096,000
#define NV   300000
#define NVH  150000           // NV/2: gather threads own rows (i, i+NVH)
#define EPS  1e-4f
#define CAP  24576            // per-tap pair capacity (expected ~21.7k, proven R4-R11)
#define CPAD 32               // counters padded: counts[idx*CPAD] = one 128B line each
#define PCAP 655360           // total pair capacity (measured ~565k, +16%)
#define TOTIDX 896            // counts int index: global pair allocator
#define NS1  (27*192)         // scat tiles in fused conv1 kernel (CAP/128 per tap)

typedef unsigned short u16;
typedef __attribute__((ext_vector_type(8))) short bf16x8;
typedef __attribute__((ext_vector_type(4))) float f32x4;

// ---- workspace layout (bytes) ----
// R14 = R13 resubmitted byte-identical: R13's "container failed twice" carried no
// compile log / pytest trace / timing JSON -> infra flake is the leading theory.
// If this fails identically again, the kernel is implicated and R15 reverts the
// dual-row gather. Concept under test: gathers are per-wave outstanding-load
// limited -> each gather thread processes TWO rows (i, i+NVH), A/B load streams
// interleaved (~2x bytes in flight per wave, unchanged chain depth), identity
// row order for coalescing. R7 GEMM structure + R10 fusions (k_prep, k_c1).
#define OFF_PART 0ull                          // PCAP*256 = 167,772,160
#define OFF_GRID 0ull                          // 16,384,000 (dies before partial writes)
#define OFF_PIN  167772160ull                  // 27*CAP*4 = 2,654,208
#define OFF_PDST (OFF_PIN  + 2654208ull)       // 27*CAP*4 = 2,654,208
#define OFF_RI   (OFF_PDST + 2654208ull)       // NV*4     = 1,200,000
#define OFF_CNT  (OFF_RI   + 1200000ull)       // 8192 (tap + total allocators)
#define OFF_H0   (OFF_CNT  + 8192ull)          // NV*64*2  = 38,400,000
#define OFF_H1   (OFF_H0   + 38400000ull)      // NV*128*2 = 76,800,000
#define OFF_W1T  (OFF_H1   + 76800000ull)      // 27*128*64*2  (B^T layout [k][cout][cin])
#define OFF_W2T  (OFF_W1T  + 442368ull)        // 27*128*128*2
#define OFF_LINW (OFF_W2T  + 884736ull)        // 128*64*2
#define OFF_BNP  (OFF_LINW + 16384ull)         // 2*128*4 (BN2 scale|shift)
#define WS_NEED  (OFF_BNP  + 1024ull)          // ~291 MB (< R5's proven 322.7)

__device__ __forceinline__ u16 f2bf(float f) {   // fp32 -> bf16 RNE
  unsigned u = __float_as_uint(f);
  return (u16)((u + 0x7fffu + ((u >> 16) & 1u)) >> 16);
}
__device__ __forceinline__ float bf2f(u16 h) {
  return __uint_as_float(((unsigned)h) << 16);
}

// ---------- phase 1: pair lists + CSR row segments (R7-proven) ----------
__global__ __launch_bounds__(256) void k_pairs(const int* __restrict__ pos,
                        const int* __restrict__ grid,
                        int* __restrict__ pin, int* __restrict__ pdst,
                        int* __restrict__ rowinfo, int* __restrict__ counts) {
  __shared__ int lcnt[27];
  __shared__ int wboff[27][4];
  __shared__ int gbase[27];
  __shared__ int scan[256];
  __shared__ int sgb;
  int t = threadIdx.x, lane = t & 63, wv = t >> 6;
  if (t < 27) lcnt[t] = 0;
  int i = blockIdx.x * 256 + t;
  bool act = (i < NV);
  int p0 = 0, p1 = 1 << 20, p2 = 0;              // inactive threads -> always OOB
  if (act) { p0 = pos[3*i]; p1 = pos[3*i+1]; p2 = pos[3*i+2]; }
  __syncthreads();                               // lcnt zeroed

  int j[26];
  #pragma unroll
  for (int kk = 0; kk < 26; kk++) {              // all 26 loads independent & in flight
    int k = kk < 13 ? kk : kk + 1;
    int q0 = p0 + k/9 - 1, q1 = p1 + (k/3)%3 - 1, q2 = p2 + k%3 - 1;
    bool inb = (q0 >= 0 && q0 < G && q1 >= 0 && q1 < G && q2 >= 0 && q2 < G);
    int addr = inb ? (q0*G + q1)*G + q2 : 0;     // clamped: unconditional load
    int jj = grid[addr];
    j[kk] = inb ? jj : -1;
  }

  unsigned vmask = 0;                            // per-row valid-tap mask (kk order)
  #pragma unroll
  for (int kk = 0; kk < 26; kk++) if (j[kk] >= 0) vmask |= 1u << kk;
  int ci = __popc(vmask);

  unsigned long long m[26];                      // wave-uniform -> SGPRs
  #pragma unroll
  for (int kk = 0; kk < 26; kk++) m[kk] = __ballot(j[kk] >= 0);

  #pragma unroll
  for (int kk = 0; kk < 26; kk++) {              // per-block aggregation in LDS
    int k = kk < 13 ? kk : kk + 1;
    if (lane == 0) wboff[k][wv] = atomicAdd(&lcnt[k], (int)__popcll(m[kk]));
  }
  scan[t] = ci;
  __syncthreads();
  #pragma unroll
  for (int d = 1; d < 256; d <<= 1) {            // Hillis-Steele inclusive scan
    int val = (t >= d) ? scan[t - d] : 0;
    __syncthreads();
    scan[t] += val;
    __syncthreads();
  }
  if (t < 27 && t != 13)                         // concurrent atomics, separate L2 lines
    gbase[t] = atomicAdd(&counts[t * CPAD], lcnt[t]);
  if (t == 255) sgb = atomicAdd(&counts[TOTIDX], scan[255]);
  __syncthreads();

  int rbase = sgb + scan[t] - ci;                // this row's CSR segment base
  int cw = (rbase + ci > PCAP) ? 0 : ci;         // overflow guard (never expected)
  if (act) rowinfo[i] = (rbase << 5) | cw;

  #pragma unroll
  for (int kk = 0; kk < 26; kk++) {
    if (j[kk] >= 0) {
      int k = kk < 13 ? kk : kk + 1;
      int slot = gbase[k] + wboff[k][wv] + (int)__popcll(m[kk] & ((1ull << lane) - 1ull));
      int dst = rbase + __popc(vmask & ((1u << kk) - 1u));
      if (slot < CAP) {
        pin[k*CAP + slot]  = j[kk];
        pdst[k*CAP + slot] = (dst < PCAP) ? dst : -1;
      }
    }
  }
}

// ---------- fused prep: BN1+ReLU->h0 | hash grid | weight cast + BN2 precompute ----------
#define NB_BN   18750                            // NV*16/256
#define NB_GRID 1172                             // (NV+255)/256
__global__ __launch_bounds__(256) void k_prep(const float* __restrict__ feat,
                          const int* __restrict__ pos, int* __restrict__ grid,
                          const float* __restrict__ g1, const float* __restrict__ b1,
                          const float* __restrict__ m1, const float* __restrict__ v1,
                          u16* __restrict__ h0,
                          const float* __restrict__ W1, const float* __restrict__ W2,
                          const float* __restrict__ linw,
                          const float* __restrict__ g2, const float* __restrict__ b2,
                          const float* __restrict__ m2, const float* __restrict__ v2,
                          u16* __restrict__ w1t, u16* __restrict__ w2t,
                          u16* __restrict__ lwt, float* __restrict__ bnp) {
  __shared__ float shf[8192];
  int b = blockIdx.x, t = threadIdx.x;
  if (b < NB_BN) {                                 // ---- BN1+ReLU -> bf16 h0 ----
    float* ss = shf; float* tt = shf + 64;
    if (t < 64) { float s = g1[t] * rsqrtf(v1[t] + EPS); ss[t] = s; tt[t] = b1[t] - m1[t]*s; }
    __syncthreads();
    long gt = (long)b * 256 + t;                   // one thread per 4 elems
    int c = (int)(gt & 15) * 4;
    float4 x = ((const float4*)feat)[gt];
    ushort4 q;
    q.x = f2bf(fmaxf(x.x*ss[c  ] + tt[c  ], 0.f));
    q.y = f2bf(fmaxf(x.y*ss[c+1] + tt[c+1], 0.f));
    q.z = f2bf(fmaxf(x.z*ss[c+2] + tt[c+2], 0.f));
    q.w = f2bf(fmaxf(x.w*ss[c+3] + tt[c+3], 0.f));
    ((ushort4*)h0)[gt] = q;
  } else if (b < NB_BN + NB_GRID) {                // ---- hash grid ----
    int i = (b - NB_BN) * 256 + t;
    if (i < NV)
      grid[(pos[3*i] * G + pos[3*i+1]) * G + pos[3*i+2]] = i;
  } else {                                         // ---- weights (56 blocks) ----
    int bb = b - NB_BN - NB_GRID;
    float* tmp = shf;
    if (bb < 27) {                                 // W1[k]: [64][128] -> [128][64]
      const float* src = W1 + bb * 8192;
      u16* dst = w1t + bb * 8192;
      for (int u = t; u < 8192; u += 256) tmp[u] = src[u];
      __syncthreads();
      for (int u = t; u < 8192; u += 256) { int c = u >> 6, a = u & 63; dst[c*64 + a] = f2bf(tmp[a*128 + c]); }
    } else if (bb < 54) {                          // W2[k]: [128][128]^T, two halves
      int k = bb - 27;
      const float* src = W2 + k * 16384;
      u16* dst = w2t + k * 16384;
      for (int h = 0; h < 2; h++) {
        for (int u = t; u < 8192; u += 256) tmp[u] = src[h*8192 + u];
        __syncthreads();
        for (int u = t; u < 8192; u += 256) { int c = u >> 6, a = u & 63; dst[c*128 + h*64 + a] = f2bf(tmp[a*128 + c]); }
        __syncthreads();
      }
    } else if (bb == 54) {                         // lin_w [128][64] already B^T
      for (int u = t; u < 8192; u += 256) lwt[u] = f2bf(linw[u]);
    } else {                                       // BN2 scale|shift
      if (t < 128) { float s = g2[t] * rsqrtf(v2[t] + EPS); bnp[t] = s; bnp[128 + t] = b2[t] - m2[t]*s; }
    }
  }
}

// ---------- GEMM building blocks (128x128 tile, 4 waves, 64x64 quadrants — R7-proven) ----------
template<int K, int RS>   // K: reduce dim; RS: global row stride (bf16 elems)
__device__ __forceinline__ void stage_rows(const u16* __restrict__ src, const int* sidx, u16* lds) {
  const int LPR = K / 8, RPI = 256 / LPR;          // 16B loaders per row, rows per iter
  int t = threadIdx.x, o = t % LPR, r0 = t / LPR;
  #pragma unroll
  for (int r = r0; r < 128; r += RPI) {
    int j = sidx[r];
    int4 val = make_int4(0, 0, 0, 0);
    if (j >= 0) val = *(const int4*)(src + (long)j * RS + o * 8);
    *(int4*)(lds + r * (K + 8) + o * 8) = val;     // +8 elem pad: low-order LDS banking
  }
}

__device__ __forceinline__ void stage_feat(const float* __restrict__ feat, int row0, u16* lds) {
  int t = threadIdx.x, o = t & 15, r0 = t >> 4;    // fp32->bf16 on the fly, K=64
  #pragma unroll
  for (int r = r0; r < 128; r += 16) {
    int row = row0 + r;
    float4 x = make_float4(0.f, 0.f, 0.f, 0.f);
    if (row < NV) x = *(const float4*)(feat + (long)row * 64 + o * 4);
    ushort4 q; q.x = f2bf(x.x); q.y = f2bf(x.y); q.z = f2bf(x.z); q.w = f2bf(x.w);
    *(ushort4*)(lds + r * 72 + o * 4) = q;
  }
}

template<int K>           // A from padded LDS; B-frags straight from L2-hot transposed weights
__device__ __forceinline__ void mma_tile(const u16* As, const u16* __restrict__ wt, f32x4 acc[4][4]) {
  int lane = threadIdx.x & 63, wave = threadIdx.x >> 6;
  int wr = (wave >> 1) * 64, wc = (wave & 1) * 64;
  int lr = lane & 15, lk = (lane >> 4) * 8;
  #pragma unroll
  for (int kk = 0; kk < K; kk += 32) {
    bf16x8 a[4], b[4];
    #pragma unroll
    for (int f = 0; f < 4; f++) a[f] = *(const bf16x8*)(As + (wr + f*16 + lr) * (K + 8) + kk + lk);
    #pragma unroll
    for (int f = 0; f < 4; f++) b[f] = *(const bf16x8*)(wt + (wc + f*16 + lr) * K + kk + lk);
    #pragma unroll
    for (int fr = 0; fr < 4; fr++)
      #pragma unroll
      for (int fc = 0; fc < 4; fc++)
        acc[fr][fc] = __builtin_amdgcn_mfma_f32_16x16x32_bf16(a[fr], b[fc], acc[fr][fc], 0, 0, 0);
  }
}

// Spill f32 acc -> bf16 LDS tile [128][136] (reuses the staging buffer).
__device__ __forceinline__ void spill_acc(const f32x4 acc[4][4], u16* As) {
  int t = threadIdx.x, lane = t & 63, wave = t >> 6;
  int wr = (wave >> 1) * 64, wc = (wave & 1) * 64, cr = (lane >> 4) * 4, cc = lane & 15;
  #pragma unroll
  for (int fr = 0; fr < 4; fr++)
    #pragma unroll
    for (int r = 0; r < 4; r++)
      #pragma unroll
      for (int fc = 0; fc < 4; fc++)
        As[(wr + fr*16 + cr + r) * 136 + wc + fc*16 + cc] = f2bf(acc[fr][fc][r]);
}

// ---------- fused conv1: scat taps (blocks < NS1) -> partial | self tap -> h1 ----------
__global__ __launch_bounds__(256, 4) void k_c1(const u16* __restrict__ h0,
                                               const u16* __restrict__ w1t,
                                               const int* __restrict__ pin,
                                               const int* __restrict__ pdst,
                                               const int* __restrict__ counts,
                                               u16* __restrict__ partial,
                                               u16* __restrict__ h1) {
  __shared__ __align__(16) u16 As[128 * 136];      // stage: [128][72]; epilogue: [128][136]
  __shared__ int sin[128], sdst[128];
  int bx = blockIdx.x, t = threadIdx.x;
  if (bx < NS1) {                                  // ---- scat path ----
    int k = bx / 192, base = (bx % 192) * 128;
    int cnt = counts[k * CPAD]; if (cnt > CAP) cnt = CAP;
    if (base >= cnt) return;                       // k==13 (cnt 0) and tail tiles exit
    if (t < 128) sin[t] = (base + t < cnt) ? pin[k*CAP + base + t] : -1;
    else         sdst[t - 128] = (base + t - 128 < cnt) ? pdst[k*CAP + base + t - 128] : -1;
    __syncthreads();
    stage_rows<64, 64>(h0, sin, As);
    __syncthreads();
    f32x4 acc[4][4] = {};
    mma_tile<64>(As, w1t + k * 8192, acc);
    __syncthreads();
    spill_acc(acc, As);
    __syncthreads();
    #pragma unroll
    for (int u = t; u < 2048; u += 256) {          // 256B-row stores to CSR destinations
      int r = u >> 4, o = u & 15;
      int d = sdst[r];
      if (d >= 0)
        *(int4*)(partial + (long)d * 128 + o * 8) = *(const int4*)(As + r * 136 + o * 8);
    }
  } else {                                         // ---- self path: dense tap 13 ----
    int row0 = (bx - NS1) * 128;
    if (t < 128) sin[t] = (row0 + t < NV) ? row0 + t : -1;
    __syncthreads();
    stage_rows<64, 64>(h0, sin, As);
    __syncthreads();
    f32x4 acc[4][4] = {};
    mma_tile<64>(As, w1t + 13 * 8192, acc);
    __syncthreads();
    spill_acc(acc, As);
    __syncthreads();
    #pragma unroll
    for (int u = t; u < 2048; u += 256) {
      int r = u >> 4, o = u & 15;
      if (row0 + r < NV)
        *(int4*)(h1 + (long)(row0 + r) * 128 + o * 8) = *(const int4*)(As + r * 136 + o * 8);
    }
  }
}

// ---------- conv2 scat: gather-GEMM K=128 -> bf16 partial rows ----------
__global__ __launch_bounds__(256, 4) void k_scat2(const u16* __restrict__ h1,
                                                  const u16* __restrict__ w2t,
                                                  const int* __restrict__ pin,
                                                  const int* __restrict__ pdst,
                                                  const int* __restrict__ counts,
                                                  u16* __restrict__ partial) {
  int k = blockIdx.y;
  int cnt = counts[k * CPAD]; if (cnt > CAP) cnt = CAP;
  int base = blockIdx.x * 128;
  if (base >= cnt) return;
  __shared__ __align__(16) u16 As[128 * 136];
  __shared__ int sin[128], sdst[128];
  int t = threadIdx.x;
  if (t < 128) sin[t] = (base + t < cnt) ? pin[k*CAP + base + t] : -1;
  else         sdst[t - 128] = (base + t - 128 < cnt) ? pdst[k*CAP + base + t - 128] : -1;
  __syncthreads();
  stage_rows<128, 128>(h1, sin, As);
  __syncthreads();
  f32x4 acc[4][4] = {};
  mma_tile<128>(As, w2t + k * 16384, acc);
  __syncthreads();
  spill_acc(acc, As);
  __syncthreads();
  #pragma unroll
  for (int u = t; u < 2048; u += 256) {
    int r = u >> 4, o = u & 15;
    int d = sdst[r];
    if (d >= 0)
      *(int4*)(partial + (long)d * 128 + o * 8) = *(const int4*)(As + r * 136 + o * 8);
  }
}

// NiN skip + self tap for conv2; writes bf16 IN PLACE over h1 (own tile staged first).
__global__ __launch_bounds__(256, 4) void k_self2(const float* __restrict__ feat,
                                                  const u16* __restrict__ lwt,
                                                  u16* __restrict__ h1,
                                                  const u16* __restrict__ w2t) {
  __shared__ __align__(16) u16 As[128 * 136];
  __shared__ int sidx[128];
  int t = threadIdx.x, row0 = blockIdx.x * 128;
  if (t < 128) sidx[t] = (row0 + t < NV) ? row0 + t : -1;
  __syncthreads();
  f32x4 acc[4][4] = {};
  stage_feat(feat, row0, As);                      // K=64 NiN pass (stride 72 region)
  __syncthreads();
  mma_tile<64>(As, lwt, acc);
  __syncthreads();
  stage_rows<128, 128>(h1, sidx, As);              // K=128 self pass (stride 136)
  __syncthreads();
  mma_tile<128>(As, w2t + 13 * 16384, acc);
  __syncthreads();
  spill_acc(acc, As);
  __syncthreads();
  #pragma unroll
  for (int u = t; u < 2048; u += 256) {
    int r = u >> 4, o = u & 15;
    if (row0 + r < NV)
      *(int4*)(h1 + (long)(row0 + r) * 128 + o * 8) = *(const int4*)(As + r * 136 + o * 8);
  }
}

// ---------- dual-row gather core: rows A,B per thread, interleaved load streams ----------
// Per iteration: up to 8 independent 16B loads (4 for A, 4 for B) issue BEFORE any
// accumulate waits -> ~2x bytes in flight per wave at unchanged chain depth.
__device__ __forceinline__ void gather_dual(int rowA, int rowB, int q,
                                            const int* __restrict__ rowinfo,
                                            const u16* __restrict__ sp,
                                            const u16* __restrict__ partial,
                                            float cA[32], float cB[32]) {
  int riA = rowinfo[rowA], riB = rowinfo[rowB];
  int baseA = (int)((unsigned)riA >> 5), cntA = riA & 31;
  int baseB = (int)((unsigned)riB >> 5), cntB = riB & 31;
  bf16x8 sA[4], sB[4];
  const u16* srA = sp + (long)rowA * 128 + q * 32;
  const u16* srB = sp + (long)rowB * 128 + q * 32;
  #pragma unroll
  for (int u = 0; u < 4; u++) sA[u] = *(const bf16x8*)(srA + u * 8);
  #pragma unroll
  for (int u = 0; u < 4; u++) sB[u] = *(const bf16x8*)(srB + u * 8);
  #pragma unroll
  for (int u = 0; u < 4; u++) {
    #pragma unroll
    for (int e = 0; e < 8; e++) {
      cA[u*8 + e] = bf2f((u16)sA[u][e]);
      cB[u*8 + e] = bf2f((u16)sB[u][e]);
    }
  }
  const u16* prA = partial + (long)baseA * 128 + q * 32;
  const u16* prB = partial + (long)baseB * 128 + q * 32;
  int mx = cntA > cntB ? cntA : cntB;
  for (int p = 0; p < mx; ++p) {
    bool va = p < cntA, vb = p < cntB;
    bf16x8 a[4], b[4];
    if (va) {
      #pragma unroll
      for (int u = 0; u < 4; u++) a[u] = *(const bf16x8*)(prA + u * 8);
    }
    if (vb) {
      #pragma unroll
      for (int u = 0; u < 4; u++) b[u] = *(const bf16x8*)(prB + u * 8);
    }
    if (va) {
      #pragma unroll
      for (int u = 0; u < 4; u++) {
        #pragma unroll
        for (int e = 0; e < 8; e++) cA[u*8 + e] += bf2f((u16)a[u][e]);
      }
    }
    if (vb) {
      #pragma unroll
      for (int u = 0; u < 4; u++) {
        #pragma unroll
        for (int e = 0; e < 8; e++) cB[u*8 + e] += bf2f((u16)b[u][e]);
      }
    }
    prA += 128; prB += 128;
  }
}

__device__ __forceinline__ void bn_store(u16* __restrict__ h1, int row, int q,
                                         const float* __restrict__ bnp, const float c[32]) {
  int col0 = q * 32;
  unsigned w[16];
  #pragma unroll
  for (int e = 0; e < 16; e++) {
    float o0 = fmaxf(c[2*e  ] * bnp[col0 + 2*e  ] + bnp[128 + col0 + 2*e  ], 0.f);
    float o1 = fmaxf(c[2*e+1] * bnp[col0 + 2*e+1] + bnp[128 + col0 + 2*e+1], 0.f);
    w[e] = (unsigned)f2bf(o0) | ((unsigned)f2bf(o1) << 16);
  }
  int4* dst = (int4*)(h1 + (long)row * 128 + col0);
  #pragma unroll
  for (int u = 0; u < 4; u++) dst[u] = make_int4(w[4*u], w[4*u+1], w[4*u+2], w[4*u+3]);
}

__device__ __forceinline__ void f32_store(float* __restrict__ out, int row, int q,
                                          const float c[32]) {
  float* dst = out + (long)row * 128 + q * 32;
  #pragma unroll
  for (int u = 0; u < 8; u++) {
    f32x4 v;
    #pragma unroll
    for (int e = 0; e < 4; e++) v[e] = c[u*4 + e];
    *(f32x4*)(dst + u * 4) = v;
  }
}

// conv1: h1 = bf16(ReLU(BN2(self + partials)))  -- in place over h1 (self pre-BN)
__global__ __launch_bounds__(256) void k_gather1(const int* __restrict__ rowinfo,
                                                 const u16* __restrict__ partial,
                                                 const float* __restrict__ bnp,
                                                 u16* __restrict__ h1) {
  long tid = (long)blockIdx.x * 256 + threadIdx.x;
  int idx = (int)(tid >> 2), q = (int)(tid & 3);
  if (idx >= NVH) return;
  int rowA = idx, rowB = idx + NVH;
  float cA[32], cB[32];
  gather_dual(rowA, rowB, q, rowinfo, h1, partial, cA, cB);
  bn_store(h1, rowA, q, bnp, cA);
  bn_store(h1, rowB, q, bnp, cB);
}

// conv2: out = f32(self(+NiN) + partials); self rides in h1 (from k_self2)
__global__ __launch_bounds__(256) void k_gather2(const int* __restrict__ rowinfo,
                                                 const u16* __restrict__ partial,
                                                 const u16* __restrict__ h1,
                                                 float* __restrict__ out) {
  long tid = (long)blockIdx.x * 256 + threadIdx.x;
  int idx = (int)(tid >> 2), q = (int)(tid & 3);
  if (idx >= NVH) return;
  int rowA = idx, rowB = idx + NVH;
  float cA[32], cB[32];
  gather_dual(rowA, rowB, q, rowinfo, h1, partial, cA, cB);
  f32_store(out, rowA, q, cA);
  f32_store(out, rowB, q, cB);
}

extern "C" void kernel_launch(void* const* d_in, const int* in_sizes, int n_in,
                              void* d_out, int out_size, void* d_ws, size_t ws_size,
                              hipStream_t stream) {
  const float* feat = (const float*)d_in[0];
  const int*   pos  = (const int*)d_in[1];
  const float* linw = (const float*)d_in[2];
  const float* g1 = (const float*)d_in[3], *b1 = (const float*)d_in[4];
  const float* m1 = (const float*)d_in[5], *v1 = (const float*)d_in[6];
  const float* W1 = (const float*)d_in[7];
  const float* g2 = (const float*)d_in[8], *b2 = (const float*)d_in[9];
  const float* m2 = (const float*)d_in[10], *v2 = (const float*)d_in[11];
  const float* W2 = (const float*)d_in[12];

  if (ws_size < WS_NEED) return;  // insufficient scratch; fail visibly rather than corrupt

  char* ws = (char*)d_ws;
  u16*   partial = (u16*)(ws + OFF_PART);
  int*   grid    = (int*)(ws + OFF_GRID);          // overlays partial head, dead before it
  int*   pin     = (int*)(ws + OFF_PIN);
  int*   pdst    = (int*)(ws + OFF_PDST);
  int*   rowinfo = (int*)(ws + OFF_RI);
  int*   counts  = (int*)(ws + OFF_CNT);
  u16*   h0      = (u16*)(ws + OFF_H0);
  u16*   h1      = (u16*)(ws + OFF_H1);
  u16*   w1t     = (u16*)(ws + OFF_W1T);
  u16*   w2t     = (u16*)(ws + OFF_W2T);
  u16*   lwt     = (u16*)(ws + OFF_LINW);
  float* bnp     = (float*)(ws + OFF_BNP);
  float* out     = (float*)d_out;

  hipMemsetAsync(grid,  0xFF, (size_t)G3 * 4, stream);       // grid = -1
  hipMemsetAsync(counts, 0, 8192, stream);                   // tap + total allocators

  k_prep <<<NB_BN + NB_GRID + 56, 256, 0, stream>>>(feat, pos, grid, g1, b1, m1, v1, h0,
                                                    W1, W2, linw, g2, b2, m2, v2,
                                                    w1t, w2t, lwt, bnp);
  k_pairs<<<(NV + 255) / 256, 256, 0, stream>>>(pos, grid, pin, pdst, rowinfo, counts);

  int nself = (NV + 127) / 128;                    // 2344 self tiles
  dim3 gg(((long)NVH * 4 + 255) / 256);            // dual-row: half the threads
  k_c1     <<<NS1 + nself, 256, 0, stream>>>(h0, w1t, pin, pdst, counts, partial, h1);
  k_gather1<<<gg, 256, 0, stream>>>(rowinfo, partial, bnp, h1);
  k_scat2  <<<dim3(192, 27), 256, 0, stream>>>(h1, w2t, pin, pdst, counts, partial);
  k_self2  <<<nself, 256, 0, stream>>>(feat, lwt, h1, w2t);
  k_gather2<<<gg, 256, 0, stream>>>(rowinfo, partial, h1, out);
}

// Round 13
// 659.433 us; speedup vs baseline: 1.0656x; 1.0173x over previous
//
#include <hip/hip_runtime.h>

#define G    160
#define G3   (G*G*G)          // 4,096,000
#define NV   300000
#define EPS  1e-4f
#define CAP  24576            // per-tap pair capacity (expected ~21.7k, proven R4-R14)
#define CPAD 32               // counters padded: counts[idx*CPAD] = one 128B line each
#define PCAP 655360           // total pair capacity (measured ~565k, +16%)
#define TOTIDX 896            // counts int index: global pair allocator
#define NS1  (27*192)         // scat tiles in fused conv1 kernel (CAP/128 per tap)
#define GGB  2048             // gather grid blocks (8192 waves, ~37 rows/wave)

typedef unsigned short u16;
typedef __attribute__((ext_vector_type(8))) short bf16x8;
typedef __attribute__((ext_vector_type(4))) float f32x4;

// ---- workspace layout (bytes) ----
// R15: gathers restructured to ONE WAVE PER ROW (R14 dual-row post-mortem: BW flat
// -> per-thread widening closed). Wave-uniform trip count (zero divergence, no
// perm), each partial row = one coalesced 256B transaction, consecutive waves own
// consecutive rows (CSR stream stays sequential), ~20 VGPR, grid-stride waves
// with next-row rowinfo prefetch. All other kernels = R14 (best, 671us).
#define OFF_PART 0ull                          // PCAP*256 = 167,772,160
#define OFF_GRID 0ull                          // 16,384,000 (dies before partial writes)
#define OFF_PIN  167772160ull                  // 27*CAP*4 = 2,654,208
#define OFF_PDST (OFF_PIN  + 2654208ull)       // 27*CAP*4 = 2,654,208
#define OFF_RI   (OFF_PDST + 2654208ull)       // NV*4     = 1,200,000
#define OFF_CNT  (OFF_RI   + 1200000ull)       // 8192 (tap + total allocators)
#define OFF_H0   (OFF_CNT  + 8192ull)          // NV*64*2  = 38,400,000
#define OFF_H1   (OFF_H0   + 38400000ull)      // NV*128*2 = 76,800,000
#define OFF_W1T  (OFF_H1   + 76800000ull)      // 27*128*64*2  (B^T layout [k][cout][cin])
#define OFF_W2T  (OFF_W1T  + 442368ull)        // 27*128*128*2
#define OFF_LINW (OFF_W2T  + 884736ull)        // 128*64*2
#define OFF_BNP  (OFF_LINW + 16384ull)         // 2*128*4 (BN2 scale|shift)
#define WS_NEED  (OFF_BNP  + 1024ull)          // ~291 MB (< R5's proven 322.7)

__device__ __forceinline__ u16 f2bf(float f) {   // fp32 -> bf16 RNE
  unsigned u = __float_as_uint(f);
  return (u16)((u + 0x7fffu + ((u >> 16) & 1u)) >> 16);
}
__device__ __forceinline__ float bf2f(u16 h) {
  return __uint_as_float(((unsigned)h) << 16);
}

// ---------- phase 1: pair lists + CSR row segments (R7-proven) ----------
__global__ __launch_bounds__(256) void k_pairs(const int* __restrict__ pos,
                        const int* __restrict__ grid,
                        int* __restrict__ pin, int* __restrict__ pdst,
                        int* __restrict__ rowinfo, int* __restrict__ counts) {
  __shared__ int lcnt[27];
  __shared__ int wboff[27][4];
  __shared__ int gbase[27];
  __shared__ int scan[256];
  __shared__ int sgb;
  int t = threadIdx.x, lane = t & 63, wv = t >> 6;
  if (t < 27) lcnt[t] = 0;
  int i = blockIdx.x * 256 + t;
  bool act = (i < NV);
  int p0 = 0, p1 = 1 << 20, p2 = 0;              // inactive threads -> always OOB
  if (act) { p0 = pos[3*i]; p1 = pos[3*i+1]; p2 = pos[3*i+2]; }
  __syncthreads();                               // lcnt zeroed

  int j[26];
  #pragma unroll
  for (int kk = 0; kk < 26; kk++) {              // all 26 loads independent & in flight
    int k = kk < 13 ? kk : kk + 1;
    int q0 = p0 + k/9 - 1, q1 = p1 + (k/3)%3 - 1, q2 = p2 + k%3 - 1;
    bool inb = (q0 >= 0 && q0 < G && q1 >= 0 && q1 < G && q2 >= 0 && q2 < G);
    int addr = inb ? (q0*G + q1)*G + q2 : 0;     // clamped: unconditional load
    int jj = grid[addr];
    j[kk] = inb ? jj : -1;
  }

  unsigned vmask = 0;                            // per-row valid-tap mask (kk order)
  #pragma unroll
  for (int kk = 0; kk < 26; kk++) if (j[kk] >= 0) vmask |= 1u << kk;
  int ci = __popc(vmask);

  unsigned long long m[26];                      // wave-uniform -> SGPRs
  #pragma unroll
  for (int kk = 0; kk < 26; kk++) m[kk] = __ballot(j[kk] >= 0);

  #pragma unroll
  for (int kk = 0; kk < 26; kk++) {              // per-block aggregation in LDS
    int k = kk < 13 ? kk : kk + 1;
    if (lane == 0) wboff[k][wv] = atomicAdd(&lcnt[k], (int)__popcll(m[kk]));
  }
  scan[t] = ci;
  __syncthreads();
  #pragma unroll
  for (int d = 1; d < 256; d <<= 1) {            // Hillis-Steele inclusive scan
    int val = (t >= d) ? scan[t - d] : 0;
    __syncthreads();
    scan[t] += val;
    __syncthreads();
  }
  if (t < 27 && t != 13)                         // concurrent atomics, separate L2 lines
    gbase[t] = atomicAdd(&counts[t * CPAD], lcnt[t]);
  if (t == 255) sgb = atomicAdd(&counts[TOTIDX], scan[255]);
  __syncthreads();

  int rbase = sgb + scan[t] - ci;                // this row's CSR segment base
  int cw = (rbase + ci > PCAP) ? 0 : ci;         // overflow guard (never expected)
  if (act) rowinfo[i] = (rbase << 5) | cw;

  #pragma unroll
  for (int kk = 0; kk < 26; kk++) {
    if (j[kk] >= 0) {
      int k = kk < 13 ? kk : kk + 1;
      int slot = gbase[k] + wboff[k][wv] + (int)__popcll(m[kk] & ((1ull << lane) - 1ull));
      int dst = rbase + __popc(vmask & ((1u << kk) - 1u));
      if (slot < CAP) {
        pin[k*CAP + slot]  = j[kk];
        pdst[k*CAP + slot] = (dst < PCAP) ? dst : -1;
      }
    }
  }
}

// ---------- fused prep: BN1+ReLU->h0 | hash grid | weight cast + BN2 precompute ----------
#define NB_BN   18750                            // NV*16/256
#define NB_GRID 1172                             // (NV+255)/256
__global__ __launch_bounds__(256) void k_prep(const float* __restrict__ feat,
                          const int* __restrict__ pos, int* __restrict__ grid,
                          const float* __restrict__ g1, const float* __restrict__ b1,
                          const float* __restrict__ m1, const float* __restrict__ v1,
                          u16* __restrict__ h0,
                          const float* __restrict__ W1, const float* __restrict__ W2,
                          const float* __restrict__ linw,
                          const float* __restrict__ g2, const float* __restrict__ b2,
                          const float* __restrict__ m2, const float* __restrict__ v2,
                          u16* __restrict__ w1t, u16* __restrict__ w2t,
                          u16* __restrict__ lwt, float* __restrict__ bnp) {
  __shared__ float shf[8192];
  int b = blockIdx.x, t = threadIdx.x;
  if (b < NB_BN) {                                 // ---- BN1+ReLU -> bf16 h0 ----
    float* ss = shf; float* tt = shf + 64;
    if (t < 64) { float s = g1[t] * rsqrtf(v1[t] + EPS); ss[t] = s; tt[t] = b1[t] - m1[t]*s; }
    __syncthreads();
    long gt = (long)b * 256 + t;                   // one thread per 4 elems
    int c = (int)(gt & 15) * 4;
    float4 x = ((const float4*)feat)[gt];
    ushort4 q;
    q.x = f2bf(fmaxf(x.x*ss[c  ] + tt[c  ], 0.f));
    q.y = f2bf(fmaxf(x.y*ss[c+1] + tt[c+1], 0.f));
    q.z = f2bf(fmaxf(x.z*ss[c+2] + tt[c+2], 0.f));
    q.w = f2bf(fmaxf(x.w*ss[c+3] + tt[c+3], 0.f));
    ((ushort4*)h0)[gt] = q;
  } else if (b < NB_BN + NB_GRID) {                // ---- hash grid ----
    int i = (b - NB_BN) * 256 + t;
    if (i < NV)
      grid[(pos[3*i] * G + pos[3*i+1]) * G + pos[3*i+2]] = i;
  } else {                                         // ---- weights (56 blocks) ----
    int bb = b - NB_BN - NB_GRID;
    float* tmp = shf;
    if (bb < 27) {                                 // W1[k]: [64][128] -> [128][64]
      const float* src = W1 + bb * 8192;
      u16* dst = w1t + bb * 8192;
      for (int u = t; u < 8192; u += 256) tmp[u] = src[u];
      __syncthreads();
      for (int u = t; u < 8192; u += 256) { int c = u >> 6, a = u & 63; dst[c*64 + a] = f2bf(tmp[a*128 + c]); }
    } else if (bb < 54) {                          // W2[k]: [128][128]^T, two halves
      int k = bb - 27;
      const float* src = W2 + k * 16384;
      u16* dst = w2t + k * 16384;
      for (int h = 0; h < 2; h++) {
        for (int u = t; u < 8192; u += 256) tmp[u] = src[h*8192 + u];
        __syncthreads();
        for (int u = t; u < 8192; u += 256) { int c = u >> 6, a = u & 63; dst[c*128 + h*64 + a] = f2bf(tmp[a*128 + c]); }
        __syncthreads();
      }
    } else if (bb == 54) {                         // lin_w [128][64] already B^T
      for (int u = t; u < 8192; u += 256) lwt[u] = f2bf(linw[u]);
    } else {                                       // BN2 scale|shift
      if (t < 128) { float s = g2[t] * rsqrtf(v2[t] + EPS); bnp[t] = s; bnp[128 + t] = b2[t] - m2[t]*s; }
    }
  }
}

// ---------- GEMM building blocks (128x128 tile, 4 waves, 64x64 quadrants — R7-proven) ----------
template<int K, int RS>   // K: reduce dim; RS: global row stride (bf16 elems)
__device__ __forceinline__ void stage_rows(const u16* __restrict__ src, const int* sidx, u16* lds) {
  const int LPR = K / 8, RPI = 256 / LPR;          // 16B loaders per row, rows per iter
  int t = threadIdx.x, o = t % LPR, r0 = t / LPR;
  #pragma unroll
  for (int r = r0; r < 128; r += RPI) {
    int j = sidx[r];
    int4 val = make_int4(0, 0, 0, 0);
    if (j >= 0) val = *(const int4*)(src + (long)j * RS + o * 8);
    *(int4*)(lds + r * (K + 8) + o * 8) = val;     // +8 elem pad: low-order LDS banking
  }
}

__device__ __forceinline__ void stage_feat(const float* __restrict__ feat, int row0, u16* lds) {
  int t = threadIdx.x, o = t & 15, r0 = t >> 4;    // fp32->bf16 on the fly, K=64
  #pragma unroll
  for (int r = r0; r < 128; r += 16) {
    int row = row0 + r;
    float4 x = make_float4(0.f, 0.f, 0.f, 0.f);
    if (row < NV) x = *(const float4*)(feat + (long)row * 64 + o * 4);
    ushort4 q; q.x = f2bf(x.x); q.y = f2bf(x.y); q.z = f2bf(x.z); q.w = f2bf(x.w);
    *(ushort4*)(lds + r * 72 + o * 4) = q;
  }
}

template<int K>           // A from padded LDS; B-frags straight from L2-hot transposed weights
__device__ __forceinline__ void mma_tile(const u16* As, const u16* __restrict__ wt, f32x4 acc[4][4]) {
  int lane = threadIdx.x & 63, wave = threadIdx.x >> 6;
  int wr = (wave >> 1) * 64, wc = (wave & 1) * 64;
  int lr = lane & 15, lk = (lane >> 4) * 8;
  #pragma unroll
  for (int kk = 0; kk < K; kk += 32) {
    bf16x8 a[4], b[4];
    #pragma unroll
    for (int f = 0; f < 4; f++) a[f] = *(const bf16x8*)(As + (wr + f*16 + lr) * (K + 8) + kk + lk);
    #pragma unroll
    for (int f = 0; f < 4; f++) b[f] = *(const bf16x8*)(wt + (wc + f*16 + lr) * K + kk + lk);
    #pragma unroll
    for (int fr = 0; fr < 4; fr++)
      #pragma unroll
      for (int fc = 0; fc < 4; fc++)
        acc[fr][fc] = __builtin_amdgcn_mfma_f32_16x16x32_bf16(a[fr], b[fc], acc[fr][fc], 0, 0, 0);
  }
}

// Spill f32 acc -> bf16 LDS tile [128][136] (reuses the staging buffer).
__device__ __forceinline__ void spill_acc(const f32x4 acc[4][4], u16* As) {
  int t = threadIdx.x, lane = t & 63, wave = t >> 6;
  int wr = (wave >> 1) * 64, wc = (wave & 1) * 64, cr = (lane >> 4) * 4, cc = lane & 15;
  #pragma unroll
  for (int fr = 0; fr < 4; fr++)
    #pragma unroll
    for (int r = 0; r < 4; r++)
      #pragma unroll
      for (int fc = 0; fc < 4; fc++)
        As[(wr + fr*16 + cr + r) * 136 + wc + fc*16 + cc] = f2bf(acc[fr][fc][r]);
}

// ---------- fused conv1: scat taps (blocks < NS1) -> partial | self tap -> h1 ----------
__global__ __launch_bounds__(256, 4) void k_c1(const u16* __restrict__ h0,
                                               const u16* __restrict__ w1t,
                                               const int* __restrict__ pin,
                                               const int* __restrict__ pdst,
                                               const int* __restrict__ counts,
                                               u16* __restrict__ partial,
                                               u16* __restrict__ h1) {
  __shared__ __align__(16) u16 As[128 * 136];      // stage: [128][72]; epilogue: [128][136]
  __shared__ int sin[128], sdst[128];
  int bx = blockIdx.x, t = threadIdx.x;
  if (bx < NS1) {                                  // ---- scat path ----
    int k = bx / 192, base = (bx % 192) * 128;
    int cnt = counts[k * CPAD]; if (cnt > CAP) cnt = CAP;
    if (base >= cnt) return;                       // k==13 (cnt 0) and tail tiles exit
    if (t < 128) sin[t] = (base + t < cnt) ? pin[k*CAP + base + t] : -1;
    else         sdst[t - 128] = (base + t - 128 < cnt) ? pdst[k*CAP + base + t - 128] : -1;
    __syncthreads();
    stage_rows<64, 64>(h0, sin, As);
    __syncthreads();
    f32x4 acc[4][4] = {};
    mma_tile<64>(As, w1t + k * 8192, acc);
    __syncthreads();
    spill_acc(acc, As);
    __syncthreads();
    #pragma unroll
    for (int u = t; u < 2048; u += 256) {          // 256B-row stores to CSR destinations
      int r = u >> 4, o = u & 15;
      int d = sdst[r];
      if (d >= 0)
        *(int4*)(partial + (long)d * 128 + o * 8) = *(const int4*)(As + r * 136 + o * 8);
    }
  } else {                                         // ---- self path: dense tap 13 ----
    int row0 = (bx - NS1) * 128;
    if (t < 128) sin[t] = (row0 + t < NV) ? row0 + t : -1;
    __syncthreads();
    stage_rows<64, 64>(h0, sin, As);
    __syncthreads();
    f32x4 acc[4][4] = {};
    mma_tile<64>(As, w1t + 13 * 8192, acc);
    __syncthreads();
    spill_acc(acc, As);
    __syncthreads();
    #pragma unroll
    for (int u = t; u < 2048; u += 256) {
      int r = u >> 4, o = u & 15;
      if (row0 + r < NV)
        *(int4*)(h1 + (long)(row0 + r) * 128 + o * 8) = *(const int4*)(As + r * 136 + o * 8);
    }
  }
}

// ---------- conv2 scat: gather-GEMM K=128 -> bf16 partial rows ----------
__global__ __launch_bounds__(256, 4) void k_scat2(const u16* __restrict__ h1,
                                                  const u16* __restrict__ w2t,
                                                  const int* __restrict__ pin,
                                                  const int* __restrict__ pdst,
                                                  const int* __restrict__ counts,
                                                  u16* __restrict__ partial) {
  int k = blockIdx.y;
  int cnt = counts[k * CPAD]; if (cnt > CAP) cnt = CAP;
  int base = blockIdx.x * 128;
  if (base >= cnt) return;
  __shared__ __align__(16) u16 As[128 * 136];
  __shared__ int sin[128], sdst[128];
  int t = threadIdx.x;
  if (t < 128) sin[t] = (base + t < cnt) ? pin[k*CAP + base + t] : -1;
  else         sdst[t - 128] = (base + t - 128 < cnt) ? pdst[k*CAP + base + t - 128] : -1;
  __syncthreads();
  stage_rows<128, 128>(h1, sin, As);
  __syncthreads();
  f32x4 acc[4][4] = {};
  mma_tile<128>(As, w2t + k * 16384, acc);
  __syncthreads();
  spill_acc(acc, As);
  __syncthreads();
  #pragma unroll
  for (int u = t; u < 2048; u += 256) {
    int r = u >> 4, o = u & 15;
    int d = sdst[r];
    if (d >= 0)
      *(int4*)(partial + (long)d * 128 + o * 8) = *(const int4*)(As + r * 136 + o * 8);
  }
}

// NiN skip + self tap for conv2; writes bf16 IN PLACE over h1 (own tile staged first).
__global__ __launch_bounds__(256, 4) void k_self2(const float* __restrict__ feat,
                                                  const u16* __restrict__ lwt,
                                                  u16* __restrict__ h1,
                                                  const u16* __restrict__ w2t) {
  __shared__ __align__(16) u16 As[128 * 136];
  __shared__ int sidx[128];
  int t = threadIdx.x, row0 = blockIdx.x * 128;
  if (t < 128) sidx[t] = (row0 + t < NV) ? row0 + t : -1;
  __syncthreads();
  f32x4 acc[4][4] = {};
  stage_feat(feat, row0, As);                      // K=64 NiN pass (stride 72 region)
  __syncthreads();
  mma_tile<64>(As, lwt, acc);
  __syncthreads();
  stage_rows<128, 128>(h1, sidx, As);              // K=128 self pass (stride 136)
  __syncthreads();
  mma_tile<128>(As, w2t + 13 * 16384, acc);
  __syncthreads();
  spill_acc(acc, As);
  __syncthreads();
  #pragma unroll
  for (int u = t; u < 2048; u += 256) {
    int r = u >> 4, o = u & 15;
    if (row0 + r < NV)
      *(int4*)(h1 + (long)(row0 + r) * 128 + o * 8) = *(const int4*)(As + r * 136 + o * 8);
  }
}

// ---------- one-wave-per-row gathers: wave-uniform trip count, coalesced 256B rows ----------
// Lane owns cols [2*lane, 2*lane+1]. Wave's 64 lanes read a full 256B partial row
// in ONE transaction; trip count = this row's cnt (uniform across the wave).
// Grid-stride rows with next-row rowinfo prefetch so row chains pipeline.

// conv1: h1 = bf16(ReLU(BN2(self + partials)))  -- in place over h1 (self pre-BN)
__global__ __launch_bounds__(256) void k_gather1(const int* __restrict__ rowinfo,
                                                 const u16* __restrict__ partial,
                                                 const float* __restrict__ bnp,
                                                 u16* __restrict__ h1) {
  int lane = threadIdx.x & 63;
  int wid  = blockIdx.x * 4 + (threadIdx.x >> 6);
  int stride = gridDim.x * 4;
  float s0 = bnp[lane*2], s1 = bnp[lane*2 + 1];        // per-lane BN params, row-invariant
  float t0 = bnp[128 + lane*2], t1 = bnp[128 + lane*2 + 1];
  int row = wid;
  if (row >= NV) return;
  int ri = rowinfo[row];
  while (true) {
    int nrow = row + stride;
    int nri = (nrow < NV) ? rowinfo[nrow] : 0;         // prefetch next row's info
    int base = (int)((unsigned)ri >> 5), cnt = ri & 31;
    unsigned sv = *(const unsigned*)(h1 + (long)row * 128 + lane*2);
    float c0 = bf2f((u16)(sv & 0xffff)), c1 = bf2f((u16)(sv >> 16));
    const u16* pr = partial + (long)base * 128 + lane*2;
    int p = 0;
    for (; p + 2 <= cnt; p += 2) {                     // 2 rows in flight
      unsigned a = *(const unsigned*)pr;
      unsigned b = *(const unsigned*)(pr + 128);
      c0 += bf2f((u16)(a & 0xffff)) + bf2f((u16)(b & 0xffff));
      c1 += bf2f((u16)(a >> 16))    + bf2f((u16)(b >> 16));
      pr += 256;
    }
    if (p < cnt) {
      unsigned a = *(const unsigned*)pr;
      c0 += bf2f((u16)(a & 0xffff));
      c1 += bf2f((u16)(a >> 16));
    }
    float o0 = fmaxf(c0 * s0 + t0, 0.f), o1 = fmaxf(c1 * s1 + t1, 0.f);
    *(unsigned*)(h1 + (long)row * 128 + lane*2) = (unsigned)f2bf(o0) | ((unsigned)f2bf(o1) << 16);
    if (nrow >= NV) break;
    row = nrow; ri = nri;
  }
}

// conv2: out = f32(self(+NiN) + partials); self rides in h1 (from k_self2)
__global__ __launch_bounds__(256) void k_gather2(const int* __restrict__ rowinfo,
                                                 const u16* __restrict__ partial,
                                                 const u16* __restrict__ h1,
                                                 float* __restrict__ out) {
  int lane = threadIdx.x & 63;
  int wid  = blockIdx.x * 4 + (threadIdx.x >> 6);
  int stride = gridDim.x * 4;
  int row = wid;
  if (row >= NV) return;
  int ri = rowinfo[row];
  while (true) {
    int nrow = row + stride;
    int nri = (nrow < NV) ? rowinfo[nrow] : 0;         // prefetch next row's info
    int base = (int)((unsigned)ri >> 5), cnt = ri & 31;
    unsigned sv = *(const unsigned*)(h1 + (long)row * 128 + lane*2);
    float c0 = bf2f((u16)(sv & 0xffff)), c1 = bf2f((u16)(sv >> 16));
    const u16* pr = partial + (long)base * 128 + lane*2;
    int p = 0;
    for (; p + 2 <= cnt; p += 2) {                     // 2 rows in flight
      unsigned a = *(const unsigned*)pr;
      unsigned b = *(const unsigned*)(pr + 128);
      c0 += bf2f((u16)(a & 0xffff)) + bf2f((u16)(b & 0xffff));
      c1 += bf2f((u16)(a >> 16))    + bf2f((u16)(b >> 16));
      pr += 256;
    }
    if (p < cnt) {
      unsigned a = *(const unsigned*)pr;
      c0 += bf2f((u16)(a & 0xffff));
      c1 += bf2f((u16)(a >> 16));
    }
    *(float2*)(out + (long)row * 128 + lane*2) = make_float2(c0, c1);
    if (nrow >= NV) break;
    row = nrow; ri = nri;
  }
}

extern "C" void kernel_launch(void* const* d_in, const int* in_sizes, int n_in,
                              void* d_out, int out_size, void* d_ws, size_t ws_size,
                              hipStream_t stream) {
  const float* feat = (const float*)d_in[0];
  const int*   pos  = (const int*)d_in[1];
  const float* linw = (const float*)d_in[2];
  const float* g1 = (const float*)d_in[3], *b1 = (const float*)d_in[4];
  const float* m1 = (const float*)d_in[5], *v1 = (const float*)d_in[6];
  const float* W1 = (const float*)d_in[7];
  const float* g2 = (const float*)d_in[8], *b2 = (const float*)d_in[9];
  const float* m2 = (const float*)d_in[10], *v2 = (const float*)d_in[11];
  const float* W2 = (const float*)d_in[12];

  if (ws_size < WS_NEED) return;  // insufficient scratch; fail visibly rather than corrupt

  char* ws = (char*)d_ws;
  u16*   partial = (u16*)(ws + OFF_PART);
  int*   grid    = (int*)(ws + OFF_GRID);          // overlays partial head, dead before it
  int*   pin     = (int*)(ws + OFF_PIN);
  int*   pdst    = (int*)(ws + OFF_PDST);
  int*   rowinfo = (int*)(ws + OFF_RI);
  int*   counts  = (int*)(ws + OFF_CNT);
  u16*   h0      = (u16*)(ws + OFF_H0);
  u16*   h1      = (u16*)(ws + OFF_H1);
  u16*   w1t     = (u16*)(ws + OFF_W1T);
  u16*   w2t     = (u16*)(ws + OFF_W2T);
  u16*   lwt     = (u16*)(ws + OFF_LINW);
  float* bnp     = (float*)(ws + OFF_BNP);
  float* out     = (float*)d_out;

  hipMemsetAsync(grid,  0xFF, (size_t)G3 * 4, stream);       // grid = -1
  hipMemsetAsync(counts, 0, 8192, stream);                   // tap + total allocators

  k_prep <<<NB_BN + NB_GRID + 56, 256, 0, stream>>>(feat, pos, grid, g1, b1, m1, v1, h0,
                                                    W1, W2, linw, g2, b2, m2, v2,
                                                    w1t, w2t, lwt, bnp);
  k_pairs<<<(NV + 255) / 256, 256, 0, stream>>>(pos, grid, pin, pdst, rowinfo, counts);

  int nself = (NV + 127) / 128;                    // 2344 self tiles
  k_c1     <<<NS1 + nself, 256, 0, stream>>>(h0, w1t, pin, pdst, counts, partial, h1);
  k_gather1<<<GGB, 256, 0, stream>>>(rowinfo, partial, bnp, h1);
  k_scat2  <<<dim3(192, 27), 256, 0, stream>>>(h1, w2t, pin, pdst, counts, partial);
  k_self2  <<<nself, 256, 0, stream>>>(feat, lwt, h1, w2t);
  k_gather2<<<GGB, 256, 0, stream>>>(rowinfo, partial, h1, out);
}

// Round 14
// 639.389 us; speedup vs baseline: 1.0990x; 1.0313x over previous
//
#include <hip/hip_runtime.h>

#define G    160
#define G3   (G*G*G)          // 4,096,000
#define NV   300000
#define EPS  1e-4f
#define CAP  24576            // per-tap pair capacity (expected ~21.7k, proven R4-R15)
#define CPAD 32               // counters padded: counts[idx*CPAD] = one 128B line each
#define PCAP 655360           // total pair capacity (measured ~565k, +16%)
#define TOTIDX 896            // counts int index: global pair allocator
#define NS1  (27*192)         // scat tiles in fused conv1 kernel (CAP/128 per tap)
#define GGB  2048             // gather grid blocks (8192 waves, ~37 rows/wave)

typedef unsigned short u16;
typedef __attribute__((ext_vector_type(8))) short bf16x8;
typedef __attribute__((ext_vector_type(4))) float f32x4;

// ---- workspace layout (bytes) ----
// R16: R15's one-wave-per-row gathers + 2-deep SOFTWARE PIPELINE (R15 post-mortem:
// store->accumulate->loads chain exposed one HBM latency per row; now row r+1's
// self + first-2-partial loads are in flight while row r accumulates, enabled by
// rowinfo prefetched TWO strides ahead). All other kernels = R15 (best, 659us).
#define OFF_PART 0ull                          // PCAP*256 = 167,772,160
#define OFF_GRID 0ull                          // 16,384,000 (dies before partial writes)
#define OFF_PIN  167772160ull                  // 27*CAP*4 = 2,654,208
#define OFF_PDST (OFF_PIN  + 2654208ull)       // 27*CAP*4 = 2,654,208
#define OFF_RI   (OFF_PDST + 2654208ull)       // NV*4     = 1,200,000
#define OFF_CNT  (OFF_RI   + 1200000ull)       // 8192 (tap + total allocators)
#define OFF_H0   (OFF_CNT  + 8192ull)          // NV*64*2  = 38,400,000
#define OFF_H1   (OFF_H0   + 38400000ull)      // NV*128*2 = 76,800,000
#define OFF_W1T  (OFF_H1   + 76800000ull)      // 27*128*64*2  (B^T layout [k][cout][cin])
#define OFF_W2T  (OFF_W1T  + 442368ull)        // 27*128*128*2
#define OFF_LINW (OFF_W2T  + 884736ull)        // 128*64*2
#define OFF_BNP  (OFF_LINW + 16384ull)         // 2*128*4 (BN2 scale|shift)
#define WS_NEED  (OFF_BNP  + 1024ull)          // ~291 MB (< R5's proven 322.7)

__device__ __forceinline__ u16 f2bf(float f) {   // fp32 -> bf16 RNE
  unsigned u = __float_as_uint(f);
  return (u16)((u + 0x7fffu + ((u >> 16) & 1u)) >> 16);
}
__device__ __forceinline__ float bf2f(u16 h) {
  return __uint_as_float(((unsigned)h) << 16);
}

// ---------- phase 1: pair lists + CSR row segments (R7-proven) ----------
__global__ __launch_bounds__(256) void k_pairs(const int* __restrict__ pos,
                        const int* __restrict__ grid,
                        int* __restrict__ pin, int* __restrict__ pdst,
                        int* __restrict__ rowinfo, int* __restrict__ counts) {
  __shared__ int lcnt[27];
  __shared__ int wboff[27][4];
  __shared__ int gbase[27];
  __shared__ int scan[256];
  __shared__ int sgb;
  int t = threadIdx.x, lane = t & 63, wv = t >> 6;
  if (t < 27) lcnt[t] = 0;
  int i = blockIdx.x * 256 + t;
  bool act = (i < NV);
  int p0 = 0, p1 = 1 << 20, p2 = 0;              // inactive threads -> always OOB
  if (act) { p0 = pos[3*i]; p1 = pos[3*i+1]; p2 = pos[3*i+2]; }
  __syncthreads();                               // lcnt zeroed

  int j[26];
  #pragma unroll
  for (int kk = 0; kk < 26; kk++) {              // all 26 loads independent & in flight
    int k = kk < 13 ? kk : kk + 1;
    int q0 = p0 + k/9 - 1, q1 = p1 + (k/3)%3 - 1, q2 = p2 + k%3 - 1;
    bool inb = (q0 >= 0 && q0 < G && q1 >= 0 && q1 < G && q2 >= 0 && q2 < G);
    int addr = inb ? (q0*G + q1)*G + q2 : 0;     // clamped: unconditional load
    int jj = grid[addr];
    j[kk] = inb ? jj : -1;
  }

  unsigned vmask = 0;                            // per-row valid-tap mask (kk order)
  #pragma unroll
  for (int kk = 0; kk < 26; kk++) if (j[kk] >= 0) vmask |= 1u << kk;
  int ci = __popc(vmask);

  unsigned long long m[26];                      // wave-uniform -> SGPRs
  #pragma unroll
  for (int kk = 0; kk < 26; kk++) m[kk] = __ballot(j[kk] >= 0);

  #pragma unroll
  for (int kk = 0; kk < 26; kk++) {              // per-block aggregation in LDS
    int k = kk < 13 ? kk : kk + 1;
    if (lane == 0) wboff[k][wv] = atomicAdd(&lcnt[k], (int)__popcll(m[kk]));
  }
  scan[t] = ci;
  __syncthreads();
  #pragma unroll
  for (int d = 1; d < 256; d <<= 1) {            // Hillis-Steele inclusive scan
    int val = (t >= d) ? scan[t - d] : 0;
    __syncthreads();
    scan[t] += val;
    __syncthreads();
  }
  if (t < 27 && t != 13)                         // concurrent atomics, separate L2 lines
    gbase[t] = atomicAdd(&counts[t * CPAD], lcnt[t]);
  if (t == 255) sgb = atomicAdd(&counts[TOTIDX], scan[255]);
  __syncthreads();

  int rbase = sgb + scan[t] - ci;                // this row's CSR segment base
  int cw = (rbase + ci > PCAP) ? 0 : ci;         // overflow guard (never expected)
  if (act) rowinfo[i] = (rbase << 5) | cw;

  #pragma unroll
  for (int kk = 0; kk < 26; kk++) {
    if (j[kk] >= 0) {
      int k = kk < 13 ? kk : kk + 1;
      int slot = gbase[k] + wboff[k][wv] + (int)__popcll(m[kk] & ((1ull << lane) - 1ull));
      int dst = rbase + __popc(vmask & ((1u << kk) - 1u));
      if (slot < CAP) {
        pin[k*CAP + slot]  = j[kk];
        pdst[k*CAP + slot] = (dst < PCAP) ? dst : -1;
      }
    }
  }
}

// ---------- fused prep: BN1+ReLU->h0 | hash grid | weight cast + BN2 precompute ----------
#define NB_BN   18750                            // NV*16/256
#define NB_GRID 1172                             // (NV+255)/256
__global__ __launch_bounds__(256) void k_prep(const float* __restrict__ feat,
                          const int* __restrict__ pos, int* __restrict__ grid,
                          const float* __restrict__ g1, const float* __restrict__ b1,
                          const float* __restrict__ m1, const float* __restrict__ v1,
                          u16* __restrict__ h0,
                          const float* __restrict__ W1, const float* __restrict__ W2,
                          const float* __restrict__ linw,
                          const float* __restrict__ g2, const float* __restrict__ b2,
                          const float* __restrict__ m2, const float* __restrict__ v2,
                          u16* __restrict__ w1t, u16* __restrict__ w2t,
                          u16* __restrict__ lwt, float* __restrict__ bnp) {
  __shared__ float shf[8192];
  int b = blockIdx.x, t = threadIdx.x;
  if (b < NB_BN) {                                 // ---- BN1+ReLU -> bf16 h0 ----
    float* ss = shf; float* tt = shf + 64;
    if (t < 64) { float s = g1[t] * rsqrtf(v1[t] + EPS); ss[t] = s; tt[t] = b1[t] - m1[t]*s; }
    __syncthreads();
    long gt = (long)b * 256 + t;                   // one thread per 4 elems
    int c = (int)(gt & 15) * 4;
    float4 x = ((const float4*)feat)[gt];
    ushort4 q;
    q.x = f2bf(fmaxf(x.x*ss[c  ] + tt[c  ], 0.f));
    q.y = f2bf(fmaxf(x.y*ss[c+1] + tt[c+1], 0.f));
    q.z = f2bf(fmaxf(x.z*ss[c+2] + tt[c+2], 0.f));
    q.w = f2bf(fmaxf(x.w*ss[c+3] + tt[c+3], 0.f));
    ((ushort4*)h0)[gt] = q;
  } else if (b < NB_BN + NB_GRID) {                // ---- hash grid ----
    int i = (b - NB_BN) * 256 + t;
    if (i < NV)
      grid[(pos[3*i] * G + pos[3*i+1]) * G + pos[3*i+2]] = i;
  } else {                                         // ---- weights (56 blocks) ----
    int bb = b - NB_BN - NB_GRID;
    float* tmp = shf;
    if (bb < 27) {                                 // W1[k]: [64][128] -> [128][64]
      const float* src = W1 + bb * 8192;
      u16* dst = w1t + bb * 8192;
      for (int u = t; u < 8192; u += 256) tmp[u] = src[u];
      __syncthreads();
      for (int u = t; u < 8192; u += 256) { int c = u >> 6, a = u & 63; dst[c*64 + a] = f2bf(tmp[a*128 + c]); }
    } else if (bb < 54) {                          // W2[k]: [128][128]^T, two halves
      int k = bb - 27;
      const float* src = W2 + k * 16384;
      u16* dst = w2t + k * 16384;
      for (int h = 0; h < 2; h++) {
        for (int u = t; u < 8192; u += 256) tmp[u] = src[h*8192 + u];
        __syncthreads();
        for (int u = t; u < 8192; u += 256) { int c = u >> 6, a = u & 63; dst[c*128 + h*64 + a] = f2bf(tmp[a*128 + c]); }
        __syncthreads();
      }
    } else if (bb == 54) {                         // lin_w [128][64] already B^T
      for (int u = t; u < 8192; u += 256) lwt[u] = f2bf(linw[u]);
    } else {                                       // BN2 scale|shift
      if (t < 128) { float s = g2[t] * rsqrtf(v2[t] + EPS); bnp[t] = s; bnp[128 + t] = b2[t] - m2[t]*s; }
    }
  }
}

// ---------- GEMM building blocks (128x128 tile, 4 waves, 64x64 quadrants — R7-proven) ----------
template<int K, int RS>   // K: reduce dim; RS: global row stride (bf16 elems)
__device__ __forceinline__ void stage_rows(const u16* __restrict__ src, const int* sidx, u16* lds) {
  const int LPR = K / 8, RPI = 256 / LPR;          // 16B loaders per row, rows per iter
  int t = threadIdx.x, o = t % LPR, r0 = t / LPR;
  #pragma unroll
  for (int r = r0; r < 128; r += RPI) {
    int j = sidx[r];
    int4 val = make_int4(0, 0, 0, 0);
    if (j >= 0) val = *(const int4*)(src + (long)j * RS + o * 8);
    *(int4*)(lds + r * (K + 8) + o * 8) = val;     // +8 elem pad: low-order LDS banking
  }
}

__device__ __forceinline__ void stage_feat(const float* __restrict__ feat, int row0, u16* lds) {
  int t = threadIdx.x, o = t & 15, r0 = t >> 4;    // fp32->bf16 on the fly, K=64
  #pragma unroll
  for (int r = r0; r < 128; r += 16) {
    int row = row0 + r;
    float4 x = make_float4(0.f, 0.f, 0.f, 0.f);
    if (row < NV) x = *(const float4*)(feat + (long)row * 64 + o * 4);
    ushort4 q; q.x = f2bf(x.x); q.y = f2bf(x.y); q.z = f2bf(x.z); q.w = f2bf(x.w);
    *(ushort4*)(lds + r * 72 + o * 4) = q;
  }
}

template<int K>           // A from padded LDS; B-frags straight from L2-hot transposed weights
__device__ __forceinline__ void mma_tile(const u16* As, const u16* __restrict__ wt, f32x4 acc[4][4]) {
  int lane = threadIdx.x & 63, wave = threadIdx.x >> 6;
  int wr = (wave >> 1) * 64, wc = (wave & 1) * 64;
  int lr = lane & 15, lk = (lane >> 4) * 8;
  #pragma unroll
  for (int kk = 0; kk < K; kk += 32) {
    bf16x8 a[4], b[4];
    #pragma unroll
    for (int f = 0; f < 4; f++) a[f] = *(const bf16x8*)(As + (wr + f*16 + lr) * (K + 8) + kk + lk);
    #pragma unroll
    for (int f = 0; f < 4; f++) b[f] = *(const bf16x8*)(wt + (wc + f*16 + lr) * K + kk + lk);
    #pragma unroll
    for (int fr = 0; fr < 4; fr++)
      #pragma unroll
      for (int fc = 0; fc < 4; fc++)
        acc[fr][fc] = __builtin_amdgcn_mfma_f32_16x16x32_bf16(a[fr], b[fc], acc[fr][fc], 0, 0, 0);
  }
}

// Spill f32 acc -> bf16 LDS tile [128][136] (reuses the staging buffer).
__device__ __forceinline__ void spill_acc(const f32x4 acc[4][4], u16* As) {
  int t = threadIdx.x, lane = t & 63, wave = t >> 6;
  int wr = (wave >> 1) * 64, wc = (wave & 1) * 64, cr = (lane >> 4) * 4, cc = lane & 15;
  #pragma unroll
  for (int fr = 0; fr < 4; fr++)
    #pragma unroll
    for (int r = 0; r < 4; r++)
      #pragma unroll
      for (int fc = 0; fc < 4; fc++)
        As[(wr + fr*16 + cr + r) * 136 + wc + fc*16 + cc] = f2bf(acc[fr][fc][r]);
}

// ---------- fused conv1: scat taps (blocks < NS1) -> partial | self tap -> h1 ----------
__global__ __launch_bounds__(256, 4) void k_c1(const u16* __restrict__ h0,
                                               const u16* __restrict__ w1t,
                                               const int* __restrict__ pin,
                                               const int* __restrict__ pdst,
                                               const int* __restrict__ counts,
                                               u16* __restrict__ partial,
                                               u16* __restrict__ h1) {
  __shared__ __align__(16) u16 As[128 * 136];      // stage: [128][72]; epilogue: [128][136]
  __shared__ int sin[128], sdst[128];
  int bx = blockIdx.x, t = threadIdx.x;
  if (bx < NS1) {                                  // ---- scat path ----
    int k = bx / 192, base = (bx % 192) * 128;
    int cnt = counts[k * CPAD]; if (cnt > CAP) cnt = CAP;
    if (base >= cnt) return;                       // k==13 (cnt 0) and tail tiles exit
    if (t < 128) sin[t] = (base + t < cnt) ? pin[k*CAP + base + t] : -1;
    else         sdst[t - 128] = (base + t - 128 < cnt) ? pdst[k*CAP + base + t - 128] : -1;
    __syncthreads();
    stage_rows<64, 64>(h0, sin, As);
    __syncthreads();
    f32x4 acc[4][4] = {};
    mma_tile<64>(As, w1t + k * 8192, acc);
    __syncthreads();
    spill_acc(acc, As);
    __syncthreads();
    #pragma unroll
    for (int u = t; u < 2048; u += 256) {          // 256B-row stores to CSR destinations
      int r = u >> 4, o = u & 15;
      int d = sdst[r];
      if (d >= 0)
        *(int4*)(partial + (long)d * 128 + o * 8) = *(const int4*)(As + r * 136 + o * 8);
    }
  } else {                                         // ---- self path: dense tap 13 ----
    int row0 = (bx - NS1) * 128;
    if (t < 128) sin[t] = (row0 + t < NV) ? row0 + t : -1;
    __syncthreads();
    stage_rows<64, 64>(h0, sin, As);
    __syncthreads();
    f32x4 acc[4][4] = {};
    mma_tile<64>(As, w1t + 13 * 8192, acc);
    __syncthreads();
    spill_acc(acc, As);
    __syncthreads();
    #pragma unroll
    for (int u = t; u < 2048; u += 256) {
      int r = u >> 4, o = u & 15;
      if (row0 + r < NV)
        *(int4*)(h1 + (long)(row0 + r) * 128 + o * 8) = *(const int4*)(As + r * 136 + o * 8);
    }
  }
}

// ---------- conv2 scat: gather-GEMM K=128 -> bf16 partial rows ----------
__global__ __launch_bounds__(256, 4) void k_scat2(const u16* __restrict__ h1,
                                                  const u16* __restrict__ w2t,
                                                  const int* __restrict__ pin,
                                                  const int* __restrict__ pdst,
                                                  const int* __restrict__ counts,
                                                  u16* __restrict__ partial) {
  int k = blockIdx.y;
  int cnt = counts[k * CPAD]; if (cnt > CAP) cnt = CAP;
  int base = blockIdx.x * 128;
  if (base >= cnt) return;
  __shared__ __align__(16) u16 As[128 * 136];
  __shared__ int sin[128], sdst[128];
  int t = threadIdx.x;
  if (t < 128) sin[t] = (base + t < cnt) ? pin[k*CAP + base + t] : -1;
  else         sdst[t - 128] = (base + t - 128 < cnt) ? pdst[k*CAP + base + t - 128] : -1;
  __syncthreads();
  stage_rows<128, 128>(h1, sin, As);
  __syncthreads();
  f32x4 acc[4][4] = {};
  mma_tile<128>(As, w2t + k * 16384, acc);
  __syncthreads();
  spill_acc(acc, As);
  __syncthreads();
  #pragma unroll
  for (int u = t; u < 2048; u += 256) {
    int r = u >> 4, o = u & 15;
    int d = sdst[r];
    if (d >= 0)
      *(int4*)(partial + (long)d * 128 + o * 8) = *(const int4*)(As + r * 136 + o * 8);
  }
}

// NiN skip + self tap for conv2; writes bf16 IN PLACE over h1 (own tile staged first).
__global__ __launch_bounds__(256, 4) void k_self2(const float* __restrict__ feat,
                                                  const u16* __restrict__ lwt,
                                                  u16* __restrict__ h1,
                                                  const u16* __restrict__ w2t) {
  __shared__ __align__(16) u16 As[128 * 136];
  __shared__ int sidx[128];
  int t = threadIdx.x, row0 = blockIdx.x * 128;
  if (t < 128) sidx[t] = (row0 + t < NV) ? row0 + t : -1;
  __syncthreads();
  f32x4 acc[4][4] = {};
  stage_feat(feat, row0, As);                      // K=64 NiN pass (stride 72 region)
  __syncthreads();
  mma_tile<64>(As, lwt, acc);
  __syncthreads();
  stage_rows<128, 128>(h1, sidx, As);              // K=128 self pass (stride 136)
  __syncthreads();
  mma_tile<128>(As, w2t + 13 * 16384, acc);
  __syncthreads();
  spill_acc(acc, As);
  __syncthreads();
  #pragma unroll
  for (int u = t; u < 2048; u += 256) {
    int r = u >> 4, o = u & 15;
    if (row0 + r < NV)
      *(int4*)(h1 + (long)(row0 + r) * 128 + o * 8) = *(const int4*)(As + r * 136 + o * 8);
  }
}

// ---------- one-wave-per-row gathers, 2-deep software pipeline ----------
// Lane owns cols [2*lane, 2*lane+1]. Trip count wave-uniform; partial row = one
// coalesced 256B transaction. While row r accumulates, row r+stride's self +
// first-2-partial loads are in flight (rowinfo prefetched TWO strides ahead).

// conv1: h1 = bf16(ReLU(BN2(self + partials)))  -- in place over h1 (self pre-BN)
__global__ __launch_bounds__(256) void k_gather1(const int* __restrict__ rowinfo,
                                                 const u16* __restrict__ partial,
                                                 const float* __restrict__ bnp,
                                                 u16* __restrict__ h1) {
  int lane = threadIdx.x & 63;
  int wid  = blockIdx.x * 4 + (threadIdx.x >> 6);
  int stride = gridDim.x * 4;
  float s0 = bnp[lane*2], s1 = bnp[lane*2 + 1];        // per-lane BN params, row-invariant
  float t0 = bnp[128 + lane*2], t1 = bnp[128 + lane*2 + 1];
  int row = wid;
  if (row >= NV) return;
  // prologue: head loads for row 0 of this wave + rowinfo one stride ahead
  int ri = rowinfo[row];
  int nrow = row + stride;
  int ri_n = (nrow < NV) ? rowinfo[nrow] : 0;
  int base = (int)((unsigned)ri >> 5), cnt = ri & 31;
  unsigned sv = *(const unsigned*)(h1 + (long)row * 128 + lane*2);
  const u16* pr = partial + (long)base * 128 + lane*2;
  unsigned p0 = 0, p1 = 0;
  if (cnt > 0) p0 = *(const unsigned*)pr;
  if (cnt > 1) p1 = *(const unsigned*)(pr + 128);
  while (true) {
    // issue NEXT row's head loads (self + first 2 partials) + rowinfo two ahead
    int nbase = 0, ncnt = 0;
    unsigned nsv = 0, np0 = 0, np1 = 0;
    const u16* npr = partial;
    if (nrow < NV) {
      nbase = (int)((unsigned)ri_n >> 5); ncnt = ri_n & 31;
      nsv = *(const unsigned*)(h1 + (long)nrow * 128 + lane*2);
      npr = partial + (long)nbase * 128 + lane*2;
      if (ncnt > 0) np0 = *(const unsigned*)npr;
      if (ncnt > 1) np1 = *(const unsigned*)(npr + 128);
    }
    int nnrow = nrow + stride;
    int ri_nn = (nnrow < NV) ? rowinfo[nnrow] : 0;
    // accumulate CURRENT row (head data already in flight/arrived)
    float c0 = bf2f((u16)(sv & 0xffff)) + bf2f((u16)(p0 & 0xffff)) + bf2f((u16)(p1 & 0xffff));
    float c1 = bf2f((u16)(sv >> 16))    + bf2f((u16)(p0 >> 16))    + bf2f((u16)(p1 >> 16));
    const u16* prt = pr + 256;                          // partial row 2 onward
    for (int p = 2; p + 2 <= cnt; p += 2) {             // 2-wide tail
      unsigned a = *(const unsigned*)prt;
      unsigned b = *(const unsigned*)(prt + 128);
      c0 += bf2f((u16)(a & 0xffff)) + bf2f((u16)(b & 0xffff));
      c1 += bf2f((u16)(a >> 16))    + bf2f((u16)(b >> 16));
      prt += 256;
    }
    if (cnt > 2 && (cnt & 1)) {                         // odd tail element
      unsigned a = *(const unsigned*)(pr + (long)(cnt - 1) * 128);
      c0 += bf2f((u16)(a & 0xffff));
      c1 += bf2f((u16)(a >> 16));
    }
    float o0 = fmaxf(c0 * s0 + t0, 0.f), o1 = fmaxf(c1 * s1 + t1, 0.f);
    *(unsigned*)(h1 + (long)row * 128 + lane*2) = (unsigned)f2bf(o0) | ((unsigned)f2bf(o1) << 16);
    if (nrow >= NV) break;
    row = nrow; cnt = ncnt; sv = nsv; p0 = np0; p1 = np1; pr = npr;
    nrow = nnrow; ri_n = ri_nn;
  }
}

// conv2: out = f32(self(+NiN) + partials); self rides in h1 (from k_self2)
__global__ __launch_bounds__(256) void k_gather2(const int* __restrict__ rowinfo,
                                                 const u16* __restrict__ partial,
                                                 const u16* __restrict__ h1,
                                                 float* __restrict__ out) {
  int lane = threadIdx.x & 63;
  int wid  = blockIdx.x * 4 + (threadIdx.x >> 6);
  int stride = gridDim.x * 4;
  int row = wid;
  if (row >= NV) return;
  int ri = rowinfo[row];
  int nrow = row + stride;
  int ri_n = (nrow < NV) ? rowinfo[nrow] : 0;
  int base = (int)((unsigned)ri >> 5), cnt = ri & 31;
  unsigned sv = *(const unsigned*)(h1 + (long)row * 128 + lane*2);
  const u16* pr = partial + (long)base * 128 + lane*2;
  unsigned p0 = 0, p1 = 0;
  if (cnt > 0) p0 = *(const unsigned*)pr;
  if (cnt > 1) p1 = *(const unsigned*)(pr + 128);
  while (true) {
    int nbase = 0, ncnt = 0;
    unsigned nsv = 0, np0 = 0, np1 = 0;
    const u16* npr = partial;
    if (nrow < NV) {
      nbase = (int)((unsigned)ri_n >> 5); ncnt = ri_n & 31;
      nsv = *(const unsigned*)(h1 + (long)nrow * 128 + lane*2);
      npr = partial + (long)nbase * 128 + lane*2;
      if (ncnt > 0) np0 = *(const unsigned*)npr;
      if (ncnt > 1) np1 = *(const unsigned*)(npr + 128);
    }
    int nnrow = nrow + stride;
    int ri_nn = (nnrow < NV) ? rowinfo[nnrow] : 0;
    float c0 = bf2f((u16)(sv & 0xffff)) + bf2f((u16)(p0 & 0xffff)) + bf2f((u16)(p1 & 0xffff));
    float c1 = bf2f((u16)(sv >> 16))    + bf2f((u16)(p0 >> 16))    + bf2f((u16)(p1 >> 16));
    const u16* prt = pr + 256;
    for (int p = 2; p + 2 <= cnt; p += 2) {
      unsigned a = *(const unsigned*)prt;
      unsigned b = *(const unsigned*)(prt + 128);
      c0 += bf2f((u16)(a & 0xffff)) + bf2f((u16)(b & 0xffff));
      c1 += bf2f((u16)(a >> 16))    + bf2f((u16)(b >> 16));
      prt += 256;
    }
    if (cnt > 2 && (cnt & 1)) {
      unsigned a = *(const unsigned*)(pr + (long)(cnt - 1) * 128);
      c0 += bf2f((u16)(a & 0xffff));
      c1 += bf2f((u16)(a >> 16));
    }
    *(float2*)(out + (long)row * 128 + lane*2) = make_float2(c0, c1);
    if (nrow >= NV) break;
    row = nrow; cnt = ncnt; sv = nsv; p0 = np0; p1 = np1; pr = npr;
    nrow = nnrow; ri_n = ri_nn;
  }
}

extern "C" void kernel_launch(void* const* d_in, const int* in_sizes, int n_in,
                              void* d_out, int out_size, void* d_ws, size_t ws_size,
                              hipStream_t stream) {
  const float* feat = (const float*)d_in[0];
  const int*   pos  = (const int*)d_in[1];
  const float* linw = (const float*)d_in[2];
  const float* g1 = (const float*)d_in[3], *b1 = (const float*)d_in[4];
  const float* m1 = (const float*)d_in[5], *v1 = (const float*)d_in[6];
  const float* W1 = (const float*)d_in[7];
  const float* g2 = (const float*)d_in[8], *b2 = (const float*)d_in[9];
  const float* m2 = (const float*)d_in[10], *v2 = (const float*)d_in[11];
  const float* W2 = (const float*)d_in[12];

  if (ws_size < WS_NEED) return;  // insufficient scratch; fail visibly rather than corrupt

  char* ws = (char*)d_ws;
  u16*   partial = (u16*)(ws + OFF_PART);
  int*   grid    = (int*)(ws + OFF_GRID);          // overlays partial head, dead before it
  int*   pin     = (int*)(ws + OFF_PIN);
  int*   pdst    = (int*)(ws + OFF_PDST);
  int*   rowinfo = (int*)(ws + OFF_RI);
  int*   counts  = (int*)(ws + OFF_CNT);
  u16*   h0      = (u16*)(ws + OFF_H0);
  u16*   h1      = (u16*)(ws + OFF_H1);
  u16*   w1t     = (u16*)(ws + OFF_W1T);
  u16*   w2t     = (u16*)(ws + OFF_W2T);
  u16*   lwt     = (u16*)(ws + OFF_LINW);
  float* bnp     = (float*)(ws + OFF_BNP);
  float* out     = (float*)d_out;

  hipMemsetAsync(grid,  0xFF, (size_t)G3 * 4, stream);       // grid = -1
  hipMemsetAsync(counts, 0, 8192, stream);                   // tap + total allocators

  k_prep <<<NB_BN + NB_GRID + 56, 256, 0, stream>>>(feat, pos, grid, g1, b1, m1, v1, h0,
                                                    W1, W2, linw, g2, b2, m2, v2,
                                                    w1t, w2t, lwt, bnp);
  k_pairs<<<(NV + 255) / 256, 256, 0, stream>>>(pos, grid, pin, pdst, rowinfo, counts);

  int nself = (NV + 127) / 128;                    // 2344 self tiles
  k_c1     <<<NS1 + nself, 256, 0, stream>>>(h0, w1t, pin, pdst, counts, partial, h1);
  k_gather1<<<GGB, 256, 0, stream>>>(rowinfo, partial, bnp, h1);
  k_scat2  <<<dim3(192, 27), 256, 0, stream>>>(h1, w2t, pin, pdst, counts, partial);
  k_self2  <<<nself, 256, 0, stream>>>(feat, lwt, h1, w2t);
  k_gather2<<<GGB, 256, 0, stream>>>(rowinfo, partial, h1, out);
}

// Round 15
// 626.711 us; speedup vs baseline: 1.1212x; 1.0202x over previous
//
#include <hip/hip_runtime.h>

#define G    160
#define G3   (G*G*G)          // 4,096,000
#define NV   300000
#define EPS  1e-4f
#define CAP  24576            // per-tap pair capacity (expected ~21.7k, proven R4-R16)
#define CPAD 32               // counters padded: counts[idx*CPAD] = one 128B line each
#define PCAP 655360           // total pair capacity (measured ~565k, +16%)
#define TOTIDX 896            // counts int index: global pair allocator
#define NS1  (27*192)         // scat tiles per conv (CAP/128 per tap)
#define GGB  2048             // gather grid blocks (8192 waves, ~37 rows/wave)

typedef unsigned short u16;
typedef __attribute__((ext_vector_type(8))) short bf16x8;
typedef __attribute__((ext_vector_type(4))) float f32x4;

// ---- workspace layout (bytes) ----
// R17: k_scat2 + k_self2 FUSED into k_c2 (same-stream kernels serialize; self2's
// ~50us dense GEMM was pure serial time after scat2's latency-bound staging).
// Enabled by giving conv2's self result its own buffer s2buf (h1 in-place hazard
// removed); k_gather2 reads self from s2buf. Gathers = R16 (pipelined, 639us).
#define OFF_PART 0ull                          // PCAP*256 = 167,772,160
#define OFF_GRID 0ull                          // 16,384,000 (dies before partial writes)
#define OFF_PIN  167772160ull                  // 27*CAP*4 = 2,654,208
#define OFF_PDST (OFF_PIN  + 2654208ull)       // 27*CAP*4 = 2,654,208
#define OFF_RI   (OFF_PDST + 2654208ull)       // NV*4     = 1,200,000
#define OFF_CNT  (OFF_RI   + 1200000ull)       // 8192 (tap + total allocators)
#define OFF_H0   (OFF_CNT  + 8192ull)          // NV*64*2  = 38,400,000
#define OFF_H1   (OFF_H0   + 38400000ull)      // NV*128*2 = 76,800,000
#define OFF_S2   (OFF_H1   + 76800000ull)      // NV*128*2 = 76,800,000 (conv2 self+NiN)
#define OFF_W1T  (OFF_S2   + 76800000ull)      // 27*128*64*2  (B^T layout [k][cout][cin])
#define OFF_W2T  (OFF_W1T  + 442368ull)        // 27*128*128*2
#define OFF_LINW (OFF_W2T  + 884736ull)        // 128*64*2
#define OFF_BNP  (OFF_LINW + 16384ull)         // 2*128*4 (BN2 scale|shift)
#define WS_NEED  (OFF_BNP  + 1024ull)          // ~368 MB (harness allocates ~614 MB)

__device__ __forceinline__ u16 f2bf(float f) {   // fp32 -> bf16 RNE
  unsigned u = __float_as_uint(f);
  return (u16)((u + 0x7fffu + ((u >> 16) & 1u)) >> 16);
}
__device__ __forceinline__ float bf2f(u16 h) {
  return __uint_as_float(((unsigned)h) << 16);
}

// ---------- phase 1: pair lists + CSR row segments (R7-proven) ----------
__global__ __launch_bounds__(256) void k_pairs(const int* __restrict__ pos,
                        const int* __restrict__ grid,
                        int* __restrict__ pin, int* __restrict__ pdst,
                        int* __restrict__ rowinfo, int* __restrict__ counts) {
  __shared__ int lcnt[27];
  __shared__ int wboff[27][4];
  __shared__ int gbase[27];
  __shared__ int scan[256];
  __shared__ int sgb;
  int t = threadIdx.x, lane = t & 63, wv = t >> 6;
  if (t < 27) lcnt[t] = 0;
  int i = blockIdx.x * 256 + t;
  bool act = (i < NV);
  int p0 = 0, p1 = 1 << 20, p2 = 0;              // inactive threads -> always OOB
  if (act) { p0 = pos[3*i]; p1 = pos[3*i+1]; p2 = pos[3*i+2]; }
  __syncthreads();                               // lcnt zeroed

  int j[26];
  #pragma unroll
  for (int kk = 0; kk < 26; kk++) {              // all 26 loads independent & in flight
    int k = kk < 13 ? kk : kk + 1;
    int q0 = p0 + k/9 - 1, q1 = p1 + (k/3)%3 - 1, q2 = p2 + k%3 - 1;
    bool inb = (q0 >= 0 && q0 < G && q1 >= 0 && q1 < G && q2 >= 0 && q2 < G);
    int addr = inb ? (q0*G + q1)*G + q2 : 0;     // clamped: unconditional load
    int jj = grid[addr];
    j[kk] = inb ? jj : -1;
  }

  unsigned vmask = 0;                            // per-row valid-tap mask (kk order)
  #pragma unroll
  for (int kk = 0; kk < 26; kk++) if (j[kk] >= 0) vmask |= 1u << kk;
  int ci = __popc(vmask);

  unsigned long long m[26];                      // wave-uniform -> SGPRs
  #pragma unroll
  for (int kk = 0; kk < 26; kk++) m[kk] = __ballot(j[kk] >= 0);

  #pragma unroll
  for (int kk = 0; kk < 26; kk++) {              // per-block aggregation in LDS
    int k = kk < 13 ? kk : kk + 1;
    if (lane == 0) wboff[k][wv] = atomicAdd(&lcnt[k], (int)__popcll(m[kk]));
  }
  scan[t] = ci;
  __syncthreads();
  #pragma unroll
  for (int d = 1; d < 256; d <<= 1) {            // Hillis-Steele inclusive scan
    int val = (t >= d) ? scan[t - d] : 0;
    __syncthreads();
    scan[t] += val;
    __syncthreads();
  }
  if (t < 27 && t != 13)                         // concurrent atomics, separate L2 lines
    gbase[t] = atomicAdd(&counts[t * CPAD], lcnt[t]);
  if (t == 255) sgb = atomicAdd(&counts[TOTIDX], scan[255]);
  __syncthreads();

  int rbase = sgb + scan[t] - ci;                // this row's CSR segment base
  int cw = (rbase + ci > PCAP) ? 0 : ci;         // overflow guard (never expected)
  if (act) rowinfo[i] = (rbase << 5) | cw;

  #pragma unroll
  for (int kk = 0; kk < 26; kk++) {
    if (j[kk] >= 0) {
      int k = kk < 13 ? kk : kk + 1;
      int slot = gbase[k] + wboff[k][wv] + (int)__popcll(m[kk] & ((1ull << lane) - 1ull));
      int dst = rbase + __popc(vmask & ((1u << kk) - 1u));
      if (slot < CAP) {
        pin[k*CAP + slot]  = j[kk];
        pdst[k*CAP + slot] = (dst < PCAP) ? dst : -1;
      }
    }
  }
}

// ---------- fused prep: BN1+ReLU->h0 | hash grid | weight cast + BN2 precompute ----------
#define NB_BN   18750                            // NV*16/256
#define NB_GRID 1172                             // (NV+255)/256
__global__ __launch_bounds__(256) void k_prep(const float* __restrict__ feat,
                          const int* __restrict__ pos, int* __restrict__ grid,
                          const float* __restrict__ g1, const float* __restrict__ b1,
                          const float* __restrict__ m1, const float* __restrict__ v1,
                          u16* __restrict__ h0,
                          const float* __restrict__ W1, const float* __restrict__ W2,
                          const float* __restrict__ linw,
                          const float* __restrict__ g2, const float* __restrict__ b2,
                          const float* __restrict__ m2, const float* __restrict__ v2,
                          u16* __restrict__ w1t, u16* __restrict__ w2t,
                          u16* __restrict__ lwt, float* __restrict__ bnp) {
  __shared__ float shf[8192];
  int b = blockIdx.x, t = threadIdx.x;
  if (b < NB_BN) {                                 // ---- BN1+ReLU -> bf16 h0 ----
    float* ss = shf; float* tt = shf + 64;
    if (t < 64) { float s = g1[t] * rsqrtf(v1[t] + EPS); ss[t] = s; tt[t] = b1[t] - m1[t]*s; }
    __syncthreads();
    long gt = (long)b * 256 + t;                   // one thread per 4 elems
    int c = (int)(gt & 15) * 4;
    float4 x = ((const float4*)feat)[gt];
    ushort4 q;
    q.x = f2bf(fmaxf(x.x*ss[c  ] + tt[c  ], 0.f));
    q.y = f2bf(fmaxf(x.y*ss[c+1] + tt[c+1], 0.f));
    q.z = f2bf(fmaxf(x.z*ss[c+2] + tt[c+2], 0.f));
    q.w = f2bf(fmaxf(x.w*ss[c+3] + tt[c+3], 0.f));
    ((ushort4*)h0)[gt] = q;
  } else if (b < NB_BN + NB_GRID) {                // ---- hash grid ----
    int i = (b - NB_BN) * 256 + t;
    if (i < NV)
      grid[(pos[3*i] * G + pos[3*i+1]) * G + pos[3*i+2]] = i;
  } else {                                         // ---- weights (56 blocks) ----
    int bb = b - NB_BN - NB_GRID;
    float* tmp = shf;
    if (bb < 27) {                                 // W1[k]: [64][128] -> [128][64]
      const float* src = W1 + bb * 8192;
      u16* dst = w1t + bb * 8192;
      for (int u = t; u < 8192; u += 256) tmp[u] = src[u];
      __syncthreads();
      for (int u = t; u < 8192; u += 256) { int c = u >> 6, a = u & 63; dst[c*64 + a] = f2bf(tmp[a*128 + c]); }
    } else if (bb < 54) {                          // W2[k]: [128][128]^T, two halves
      int k = bb - 27;
      const float* src = W2 + k * 16384;
      u16* dst = w2t + k * 16384;
      for (int h = 0; h < 2; h++) {
        for (int u = t; u < 8192; u += 256) tmp[u] = src[h*8192 + u];
        __syncthreads();
        for (int u = t; u < 8192; u += 256) { int c = u >> 6, a = u & 63; dst[c*128 + h*64 + a] = f2bf(tmp[a*128 + c]); }
        __syncthreads();
      }
    } else if (bb == 54) {                         // lin_w [128][64] already B^T
      for (int u = t; u < 8192; u += 256) lwt[u] = f2bf(linw[u]);
    } else {                                       // BN2 scale|shift
      if (t < 128) { float s = g2[t] * rsqrtf(v2[t] + EPS); bnp[t] = s; bnp[128 + t] = b2[t] - m2[t]*s; }
    }
  }
}

// ---------- GEMM building blocks (128x128 tile, 4 waves, 64x64 quadrants — R7-proven) ----------
template<int K, int RS>   // K: reduce dim; RS: global row stride (bf16 elems)
__device__ __forceinline__ void stage_rows(const u16* __restrict__ src, const int* sidx, u16* lds) {
  const int LPR = K / 8, RPI = 256 / LPR;          // 16B loaders per row, rows per iter
  int t = threadIdx.x, o = t % LPR, r0 = t / LPR;
  #pragma unroll
  for (int r = r0; r < 128; r += RPI) {
    int j = sidx[r];
    int4 val = make_int4(0, 0, 0, 0);
    if (j >= 0) val = *(const int4*)(src + (long)j * RS + o * 8);
    *(int4*)(lds + r * (K + 8) + o * 8) = val;     // +8 elem pad: low-order LDS banking
  }
}

__device__ __forceinline__ void stage_feat(const float* __restrict__ feat, int row0, u16* lds) {
  int t = threadIdx.x, o = t & 15, r0 = t >> 4;    // fp32->bf16 on the fly, K=64
  #pragma unroll
  for (int r = r0; r < 128; r += 16) {
    int row = row0 + r;
    float4 x = make_float4(0.f, 0.f, 0.f, 0.f);
    if (row < NV) x = *(const float4*)(feat + (long)row * 64 + o * 4);
    ushort4 q; q.x = f2bf(x.x); q.y = f2bf(x.y); q.z = f2bf(x.z); q.w = f2bf(x.w);
    *(ushort4*)(lds + r * 72 + o * 4) = q;
  }
}

template<int K>           // A from padded LDS; B-frags straight from L2-hot transposed weights
__device__ __forceinline__ void mma_tile(const u16* As, const u16* __restrict__ wt, f32x4 acc[4][4]) {
  int lane = threadIdx.x & 63, wave = threadIdx.x >> 6;
  int wr = (wave >> 1) * 64, wc = (wave & 1) * 64;
  int lr = lane & 15, lk = (lane >> 4) * 8;
  #pragma unroll
  for (int kk = 0; kk < K; kk += 32) {
    bf16x8 a[4], b[4];
    #pragma unroll
    for (int f = 0; f < 4; f++) a[f] = *(const bf16x8*)(As + (wr + f*16 + lr) * (K + 8) + kk + lk);
    #pragma unroll
    for (int f = 0; f < 4; f++) b[f] = *(const bf16x8*)(wt + (wc + f*16 + lr) * K + kk + lk);
    #pragma unroll
    for (int fr = 0; fr < 4; fr++)
      #pragma unroll
      for (int fc = 0; fc < 4; fc++)
        acc[fr][fc] = __builtin_amdgcn_mfma_f32_16x16x32_bf16(a[fr], b[fc], acc[fr][fc], 0, 0, 0);
  }
}

// Spill f32 acc -> bf16 LDS tile [128][136] (reuses the staging buffer).
__device__ __forceinline__ void spill_acc(const f32x4 acc[4][4], u16* As) {
  int t = threadIdx.x, lane = t & 63, wave = t >> 6;
  int wr = (wave >> 1) * 64, wc = (wave & 1) * 64, cr = (lane >> 4) * 4, cc = lane & 15;
  #pragma unroll
  for (int fr = 0; fr < 4; fr++)
    #pragma unroll
    for (int r = 0; r < 4; r++)
      #pragma unroll
      for (int fc = 0; fc < 4; fc++)
        As[(wr + fr*16 + cr + r) * 136 + wc + fc*16 + cc] = f2bf(acc[fr][fc][r]);
}

// ---------- fused conv1: scat taps (blocks < NS1) -> partial | self tap -> h1 ----------
__global__ __launch_bounds__(256, 4) void k_c1(const u16* __restrict__ h0,
                                               const u16* __restrict__ w1t,
                                               const int* __restrict__ pin,
                                               const int* __restrict__ pdst,
                                               const int* __restrict__ counts,
                                               u16* __restrict__ partial,
                                               u16* __restrict__ h1) {
  __shared__ __align__(16) u16 As[128 * 136];      // stage: [128][72]; epilogue: [128][136]
  __shared__ int sin[128], sdst[128];
  int bx = blockIdx.x, t = threadIdx.x;
  if (bx < NS1) {                                  // ---- scat path ----
    int k = bx / 192, base = (bx % 192) * 128;
    int cnt = counts[k * CPAD]; if (cnt > CAP) cnt = CAP;
    if (base >= cnt) return;                       // k==13 (cnt 0) and tail tiles exit
    if (t < 128) sin[t] = (base + t < cnt) ? pin[k*CAP + base + t] : -1;
    else         sdst[t - 128] = (base + t - 128 < cnt) ? pdst[k*CAP + base + t - 128] : -1;
    __syncthreads();
    stage_rows<64, 64>(h0, sin, As);
    __syncthreads();
    f32x4 acc[4][4] = {};
    mma_tile<64>(As, w1t + k * 8192, acc);
    __syncthreads();
    spill_acc(acc, As);
    __syncthreads();
    #pragma unroll
    for (int u = t; u < 2048; u += 256) {          // 256B-row stores to CSR destinations
      int r = u >> 4, o = u & 15;
      int d = sdst[r];
      if (d >= 0)
        *(int4*)(partial + (long)d * 128 + o * 8) = *(const int4*)(As + r * 136 + o * 8);
    }
  } else {                                         // ---- self path: dense tap 13 ----
    int row0 = (bx - NS1) * 128;
    if (t < 128) sin[t] = (row0 + t < NV) ? row0 + t : -1;
    __syncthreads();
    stage_rows<64, 64>(h0, sin, As);
    __syncthreads();
    f32x4 acc[4][4] = {};
    mma_tile<64>(As, w1t + 13 * 8192, acc);
    __syncthreads();
    spill_acc(acc, As);
    __syncthreads();
    #pragma unroll
    for (int u = t; u < 2048; u += 256) {
      int r = u >> 4, o = u & 15;
      if (row0 + r < NV)
        *(int4*)(h1 + (long)(row0 + r) * 128 + o * 8) = *(const int4*)(As + r * 136 + o * 8);
    }
  }
}

// ---------- fused conv2: scat taps (blocks < NS1) -> partial | NiN+self -> s2buf ----------
// Self result goes to s2buf (NOT h1): removes the in-place hazard that forced
// scat2/self2 into separate serialized launches.
__global__ __launch_bounds__(256, 4) void k_c2(const float* __restrict__ feat,
                                               const u16* __restrict__ lwt,
                                               const u16* __restrict__ h1,
                                               const u16* __restrict__ w2t,
                                               const int* __restrict__ pin,
                                               const int* __restrict__ pdst,
                                               const int* __restrict__ counts,
                                               u16* __restrict__ partial,
                                               u16* __restrict__ s2buf) {
  __shared__ __align__(16) u16 As[128 * 136];
  __shared__ int sin[128], sdst[128];
  int bx = blockIdx.x, t = threadIdx.x;
  if (bx < NS1) {                                  // ---- scat path: K=128 tap GEMM ----
    int k = bx / 192, base = (bx % 192) * 128;
    int cnt = counts[k * CPAD]; if (cnt > CAP) cnt = CAP;
    if (base >= cnt) return;
    if (t < 128) sin[t] = (base + t < cnt) ? pin[k*CAP + base + t] : -1;
    else         sdst[t - 128] = (base + t - 128 < cnt) ? pdst[k*CAP + base + t - 128] : -1;
    __syncthreads();
    stage_rows<128, 128>(h1, sin, As);
    __syncthreads();
    f32x4 acc[4][4] = {};
    mma_tile<128>(As, w2t + k * 16384, acc);
    __syncthreads();
    spill_acc(acc, As);
    __syncthreads();
    #pragma unroll
    for (int u = t; u < 2048; u += 256) {
      int r = u >> 4, o = u & 15;
      int d = sdst[r];
      if (d >= 0)
        *(int4*)(partial + (long)d * 128 + o * 8) = *(const int4*)(As + r * 136 + o * 8);
    }
  } else {                                         // ---- self path: NiN + tap 13 -> s2buf ----
    int row0 = (bx - NS1) * 128;
    if (t < 128) sin[t] = (row0 + t < NV) ? row0 + t : -1;
    __syncthreads();
    f32x4 acc[4][4] = {};
    stage_feat(feat, row0, As);                    // K=64 NiN pass (stride 72 region)
    __syncthreads();
    mma_tile<64>(As, lwt, acc);
    __syncthreads();
    stage_rows<128, 128>(h1, sin, As);             // K=128 self pass (stride 136)
    __syncthreads();
    mma_tile<128>(As, w2t + 13 * 16384, acc);
    __syncthreads();
    spill_acc(acc, As);
    __syncthreads();
    #pragma unroll
    for (int u = t; u < 2048; u += 256) {
      int r = u >> 4, o = u & 15;
      if (row0 + r < NV)
        *(int4*)(s2buf + (long)(row0 + r) * 128 + o * 8) = *(const int4*)(As + r * 136 + o * 8);
    }
  }
}

// ---------- one-wave-per-row gathers, 2-deep software pipeline (R16-proven) ----------
// Lane owns cols [2*lane, 2*lane+1]. Trip count wave-uniform; partial row = one
// coalesced 256B transaction. While row r accumulates, row r+stride's self +
// first-2-partial loads are in flight (rowinfo prefetched TWO strides ahead).

// conv1: h1 = bf16(ReLU(BN2(self + partials)))  -- in place over h1 (self pre-BN)
__global__ __launch_bounds__(256) void k_gather1(const int* __restrict__ rowinfo,
                                                 const u16* __restrict__ partial,
                                                 const float* __restrict__ bnp,
                                                 u16* __restrict__ h1) {
  int lane = threadIdx.x & 63;
  int wid  = blockIdx.x * 4 + (threadIdx.x >> 6);
  int stride = gridDim.x * 4;
  float s0 = bnp[lane*2], s1 = bnp[lane*2 + 1];        // per-lane BN params, row-invariant
  float t0 = bnp[128 + lane*2], t1 = bnp[128 + lane*2 + 1];
  int row = wid;
  if (row >= NV) return;
  int ri = rowinfo[row];
  int nrow = row + stride;
  int ri_n = (nrow < NV) ? rowinfo[nrow] : 0;
  int base = (int)((unsigned)ri >> 5), cnt = ri & 31;
  unsigned sv = *(const unsigned*)(h1 + (long)row * 128 + lane*2);
  const u16* pr = partial + (long)base * 128 + lane*2;
  unsigned p0 = 0, p1 = 0;
  if (cnt > 0) p0 = *(const unsigned*)pr;
  if (cnt > 1) p1 = *(const unsigned*)(pr + 128);
  while (true) {
    int nbase = 0, ncnt = 0;
    unsigned nsv = 0, np0 = 0, np1 = 0;
    const u16* npr = partial;
    if (nrow < NV) {
      nbase = (int)((unsigned)ri_n >> 5); ncnt = ri_n & 31;
      nsv = *(const unsigned*)(h1 + (long)nrow * 128 + lane*2);
      npr = partial + (long)nbase * 128 + lane*2;
      if (ncnt > 0) np0 = *(const unsigned*)npr;
      if (ncnt > 1) np1 = *(const unsigned*)(npr + 128);
    }
    int nnrow = nrow + stride;
    int ri_nn = (nnrow < NV) ? rowinfo[nnrow] : 0;
    float c0 = bf2f((u16)(sv & 0xffff)) + bf2f((u16)(p0 & 0xffff)) + bf2f((u16)(p1 & 0xffff));
    float c1 = bf2f((u16)(sv >> 16))    + bf2f((u16)(p0 >> 16))    + bf2f((u16)(p1 >> 16));
    const u16* prt = pr + 256;                          // partial row 2 onward
    for (int p = 2; p + 2 <= cnt; p += 2) {             // 2-wide tail
      unsigned a = *(const unsigned*)prt;
      unsigned b = *(const unsigned*)(prt + 128);
      c0 += bf2f((u16)(a & 0xffff)) + bf2f((u16)(b & 0xffff));
      c1 += bf2f((u16)(a >> 16))    + bf2f((u16)(b >> 16));
      prt += 256;
    }
    if (cnt > 2 && (cnt & 1)) {                         // odd tail element
      unsigned a = *(const unsigned*)(pr + (long)(cnt - 1) * 128);
      c0 += bf2f((u16)(a & 0xffff));
      c1 += bf2f((u16)(a >> 16));
    }
    float o0 = fmaxf(c0 * s0 + t0, 0.f), o1 = fmaxf(c1 * s1 + t1, 0.f);
    *(unsigned*)(h1 + (long)row * 128 + lane*2) = (unsigned)f2bf(o0) | ((unsigned)f2bf(o1) << 16);
    if (nrow >= NV) break;
    row = nrow; cnt = ncnt; sv = nsv; p0 = np0; p1 = np1; pr = npr;
    nrow = nnrow; ri_n = ri_nn;
  }
}

// conv2: out = f32(self(+NiN) + partials); self rides in s2buf (from k_c2)
__global__ __launch_bounds__(256) void k_gather2(const int* __restrict__ rowinfo,
                                                 const u16* __restrict__ partial,
                                                 const u16* __restrict__ s2buf,
                                                 float* __restrict__ out) {
  int lane = threadIdx.x & 63;
  int wid  = blockIdx.x * 4 + (threadIdx.x >> 6);
  int stride = gridDim.x * 4;
  int row = wid;
  if (row >= NV) return;
  int ri = rowinfo[row];
  int nrow = row + stride;
  int ri_n = (nrow < NV) ? rowinfo[nrow] : 0;
  int base = (int)((unsigned)ri >> 5), cnt = ri & 31;
  unsigned sv = *(const unsigned*)(s2buf + (long)row * 128 + lane*2);
  const u16* pr = partial + (long)base * 128 + lane*2;
  unsigned p0 = 0, p1 = 0;
  if (cnt > 0) p0 = *(const unsigned*)pr;
  if (cnt > 1) p1 = *(const unsigned*)(pr + 128);
  while (true) {
    int nbase = 0, ncnt = 0;
    unsigned nsv = 0, np0 = 0, np1 = 0;
    const u16* npr = partial;
    if (nrow < NV) {
      nbase = (int)((unsigned)ri_n >> 5); ncnt = ri_n & 31;
      nsv = *(const unsigned*)(s2buf + (long)nrow * 128 + lane*2);
      npr = partial + (long)nbase * 128 + lane*2;
      if (ncnt > 0) np0 = *(const unsigned*)npr;
      if (ncnt > 1) np1 = *(const unsigned*)(npr + 128);
    }
    int nnrow = nrow + stride;
    int ri_nn = (nnrow < NV) ? rowinfo[nnrow] : 0;
    float c0 = bf2f((u16)(sv & 0xffff)) + bf2f((u16)(p0 & 0xffff)) + bf2f((u16)(p1 & 0xffff));
    float c1 = bf2f((u16)(sv >> 16))    + bf2f((u16)(p0 >> 16))    + bf2f((u16)(p1 >> 16));
    const u16* prt = pr + 256;
    for (int p = 2; p + 2 <= cnt; p += 2) {
      unsigned a = *(const unsigned*)prt;
      unsigned b = *(const unsigned*)(prt + 128);
      c0 += bf2f((u16)(a & 0xffff)) + bf2f((u16)(b & 0xffff));
      c1 += bf2f((u16)(a >> 16))    + bf2f((u16)(b >> 16));
      prt += 256;
    }
    if (cnt > 2 && (cnt & 1)) {
      unsigned a = *(const unsigned*)(pr + (long)(cnt - 1) * 128);
      c0 += bf2f((u16)(a & 0xffff));
      c1 += bf2f((u16)(a >> 16));
    }
    *(float2*)(out + (long)row * 128 + lane*2) = make_float2(c0, c1);
    if (nrow >= NV) break;
    row = nrow; cnt = ncnt; sv = nsv; p0 = np0; p1 = np1; pr = npr;
    nrow = nnrow; ri_n = ri_nn;
  }
}

extern "C" void kernel_launch(void* const* d_in, const int* in_sizes, int n_in,
                              void* d_out, int out_size, void* d_ws, size_t ws_size,
                              hipStream_t stream) {
  const float* feat = (const float*)d_in[0];
  const int*   pos  = (const int*)d_in[1];
  const float* linw = (const float*)d_in[2];
  const float* g1 = (const float*)d_in[3], *b1 = (const float*)d_in[4];
  const float* m1 = (const float*)d_in[5], *v1 = (const float*)d_in[6];
  const float* W1 = (const float*)d_in[7];
  const float* g2 = (const float*)d_in[8], *b2 = (const float*)d_in[9];
  const float* m2 = (const float*)d_in[10], *v2 = (const float*)d_in[11];
  const float* W2 = (const float*)d_in[12];

  if (ws_size < WS_NEED) return;  // insufficient scratch; fail visibly rather than corrupt

  char* ws = (char*)d_ws;
  u16*   partial = (u16*)(ws + OFF_PART);
  int*   grid    = (int*)(ws + OFF_GRID);          // overlays partial head, dead before it
  int*   pin     = (int*)(ws + OFF_PIN);
  int*   pdst    = (int*)(ws + OFF_PDST);
  int*   rowinfo = (int*)(ws + OFF_RI);
  int*   counts  = (int*)(ws + OFF_CNT);
  u16*   h0      = (u16*)(ws + OFF_H0);
  u16*   h1      = (u16*)(ws + OFF_H1);
  u16*   s2buf   = (u16*)(ws + OFF_S2);
  u16*   w1t     = (u16*)(ws + OFF_W1T);
  u16*   w2t     = (u16*)(ws + OFF_W2T);
  u16*   lwt     = (u16*)(ws + OFF_LINW);
  float* bnp     = (float*)(ws + OFF_BNP);
  float* out     = (float*)d_out;

  hipMemsetAsync(grid,  0xFF, (size_t)G3 * 4, stream);       // grid = -1
  hipMemsetAsync(counts, 0, 8192, stream);                   // tap + total allocators

  k_prep <<<NB_BN + NB_GRID + 56, 256, 0, stream>>>(feat, pos, grid, g1, b1, m1, v1, h0,
                                                    W1, W2, linw, g2, b2, m2, v2,
                                                    w1t, w2t, lwt, bnp);
  k_pairs<<<(NV + 255) / 256, 256, 0, stream>>>(pos, grid, pin, pdst, rowinfo, counts);

  int nself = (NV + 127) / 128;                    // 2344 self tiles
  k_c1     <<<NS1 + nself, 256, 0, stream>>>(h0, w1t, pin, pdst, counts, partial, h1);
  k_gather1<<<GGB, 256, 0, stream>>>(rowinfo, partial, bnp, h1);
  k_c2     <<<NS1 + nself, 256, 0, stream>>>(feat, lwt, h1, w2t, pin, pdst, counts, partial, s2buf);
  k_gather2<<<GGB, 256, 0, stream>>>(rowinfo, partial, s2buf, out);
}